// Round 8
// baseline (716.954 us; speedup 1.0000x reference)
//
#include <hip/hip_runtime.h>

// ---------------------------------------------------------------------------
// PipelinedMoEBlock: LN1 -> QKV -> causal MHA -> Wo+res -> LN2 -> top2 MoE -> res
// B=8 T=1024 D=512 H=8 HD=64 E=8 K=2 F=2048  (Ntok = 8192)
//
// Numerics: pre-gating path uses split-bf16 compensated MFMA (~f32 accuracy)
// so the top-2 routing matches the f32 reference; experts are plain bf16.
// R1: routing atomics wave-aggregated (ballot).
// R2: 2-phase double-buffered K-loop in all MFMA GEMMs; MoE grid flattened.
// R3: attn: T14 register prefetch, LPT order, XCD head-affinity, setprio.
// R4: MoE GEMMs: XCD band-supertile remap (FETCH 169->33.6 MB) + gelu sigmoid.
// R5: MoE BK=32, 32KB LDS -> multi-block/CU.
// R6: conflict-free LDS swizzle kcs = lg ^ ((row>>1)&3) (4.36M conflicts -> 0).
// R7: revert R6's 3-deep counted-vmcnt (regressed: occ 23->18.5%, dur 100->124;
//     T4 is null outside 8-phase schedules — m230). Back to 2-deep dbuf +
//     swizzle fix + launch_bounds(256,5): 5 blocks/CU (160KB LDS exactly) —
//     inter-block overlap (m97/m114) is the mechanism that pays here.
// ---------------------------------------------------------------------------

typedef unsigned short u16;
typedef unsigned int   u32;
typedef unsigned long long u64;
typedef __attribute__((ext_vector_type(8))) short short8;
typedef __attribute__((ext_vector_type(4))) float f32x4;

#define DEV static __device__ __forceinline__

DEV u16 f2bf(float f){
  union { float f; u32 u; } x; x.f = f;
  return (u16)((x.u + 0x7FFFu + ((x.u >> 16) & 1u)) >> 16);
}
DEV float bf2f(u16 b){
  union { u32 u; float f; } x; x.u = ((u32)b) << 16; return x.f;
}
DEV f32x4 mfma16(short8 a, short8 b, f32x4 c){
  return __builtin_amdgcn_mfma_f32_16x16x32_bf16(a, b, c, 0, 0, 0);
}
DEV void g2l16(const void* g, void* l){
  __builtin_amdgcn_global_load_lds((const __attribute__((address_space(1))) u32*)g,
                                   (__attribute__((address_space(3))) u32*)l, 16, 0, 0);
}
DEV void wait_vm0(){ asm volatile("s_waitcnt vmcnt(0)" ::: "memory"); }

// ---------------------------------------------------------------------------
// Weight transpose + f32 -> bf16 (split-2 and single variants)
// ---------------------------------------------------------------------------
__global__ __launch_bounds__(256) void transpose_cvt2(const float* __restrict__ src,
    u16* __restrict__ dh, u16* __restrict__ dl, int R, int C)
{
  __shared__ float tile[32][33];
  const size_t zb = (size_t)blockIdx.z * R * C;
  src += zb; dh += zb; dl += zb;
  const int tx = threadIdx.x, ty = threadIdx.y;
  const int c0 = blockIdx.x * 32, r0 = blockIdx.y * 32;
  #pragma unroll
  for (int i = 0; i < 4; ++i)
    tile[ty + i*8][tx] = src[(size_t)(r0 + ty + i*8) * C + c0 + tx];
  __syncthreads();
  #pragma unroll
  for (int i = 0; i < 4; ++i){
    float v = tile[tx][ty + i*8];
    size_t o = (size_t)(c0 + ty + i*8) * R + r0 + tx;
    u16 hb = f2bf(v);
    dh[o] = hb;
    dl[o] = f2bf(v - bf2f(hb));
  }
}

__global__ __launch_bounds__(256) void transpose_cvt1(const float* __restrict__ src,
    u16* __restrict__ d, int R, int C)
{
  __shared__ float tile[32][33];
  const size_t zb = (size_t)blockIdx.z * R * C;
  src += zb; d += zb;
  const int tx = threadIdx.x, ty = threadIdx.y;
  const int c0 = blockIdx.x * 32, r0 = blockIdx.y * 32;
  #pragma unroll
  for (int i = 0; i < 4; ++i)
    tile[ty + i*8][tx] = src[(size_t)(r0 + ty + i*8) * C + c0 + tx];
  __syncthreads();
  #pragma unroll
  for (int i = 0; i < 4; ++i)
    d[(size_t)(c0 + ty + i*8) * R + r0 + tx] = f2bf(tile[tx][ty + i*8]);
}

// ---------------------------------------------------------------------------
// LN1: one wave per row, write y1 as split-2 bf16
// ---------------------------------------------------------------------------
__global__ __launch_bounds__(256) void ln1_kernel(const float* __restrict__ x,
    const float* __restrict__ g, const float* __restrict__ b,
    u16* __restrict__ yh, u16* __restrict__ yl)
{
  const int wid = threadIdx.x >> 6, lane = threadIdx.x & 63;
  const int row = blockIdx.x * 4 + wid;
  const float* xr = x + (size_t)row * 512 + lane * 8;
  f32x4 t0 = ((const f32x4*)xr)[0], t1 = ((const f32x4*)xr)[1];
  float v[8];
  #pragma unroll
  for (int j = 0; j < 8; ++j) v[j] = (j < 4) ? t0[j] : t1[j-4];
  float s = 0.f, q = 0.f;
  #pragma unroll
  for (int j = 0; j < 8; ++j){ s += v[j]; q += v[j]*v[j]; }
  #pragma unroll
  for (int o = 32; o; o >>= 1){ s += __shfl_xor(s, o); q += __shfl_xor(q, o); }
  const float mean = s * (1.f/512.f);
  const float var  = q * (1.f/512.f) - mean*mean;
  const float rstd = rsqrtf(var + 1e-5f);
  f32x4 g0 = ((const f32x4*)(g + lane*8))[0], g1 = ((const f32x4*)(g + lane*8))[1];
  f32x4 b0 = ((const f32x4*)(b + lane*8))[0], b1 = ((const f32x4*)(b + lane*8))[1];
  short8 vh, vl;
  #pragma unroll
  for (int j = 0; j < 8; ++j){
    float gg = (j < 4) ? g0[j] : g1[j-4];
    float bb = (j < 4) ? b0[j] : b1[j-4];
    float y = (v[j]-mean)*rstd*gg + bb;
    u16 hb = f2bf(y);
    vh[j] = (short)hb;
    vl[j] = (short)f2bf(y - bf2f(hb));
  }
  ((short8*)(yh + (size_t)row*512 + lane*8))[0] = vh;
  ((short8*)(yl + (size_t)row*512 + lane*8))[0] = vl;
}

// ---------------------------------------------------------------------------
// Split-2 GEMM: C = (Ah+Al) @ (Bh+Bl)^T, 3 MFMA passes. 128x128 tile, BK=32.
// 2-phase double-buffered K-loop. R6 swizzle: kcs = lg ^ ((row>>1)&3).
// ---------------------------------------------------------------------------
template<int MODE>
__global__ __launch_bounds__(256) void gemm_split2(
    const u16* __restrict__ Ah, const u16* __restrict__ Al,
    const u16* __restrict__ Bh, const u16* __restrict__ Bl,
    const float* __restrict__ bias, int K,
    u16* __restrict__ q_h, u16* __restrict__ q_l, u16* __restrict__ q_m,
    u16* __restrict__ k_h, u16* __restrict__ k_l, u16* __restrict__ k_m,
    u16* __restrict__ v_h, u16* __restrict__ v_l,
    const float* __restrict__ xres, float* __restrict__ hout)
{
  __shared__ u16 Ash[2][128*32], Asl[2][128*32], Bsh[2][128*32], Bsl[2][128*32];
  const int tid = threadIdx.x;
  const int wid = tid >> 6, lane = tid & 63;
  const int wr = wid >> 1, wc = wid & 1;
  const int lr = lane & 15, lg = lane >> 4;
  const int m0 = blockIdx.x * 128, n0 = blockIdx.y * 128;

  size_t aoff[2], boff[2];
  u32 ldso[2];
  #pragma unroll
  for (int r = 0; r < 2; ++r){
    int i = r*256 + tid;
    int row = i >> 2, cc = i & 3;
    int scc = cc ^ ((row >> 1) & 3);      // pre-swizzled source chunk (R6)
    aoff[r] = ((size_t)(m0+row)*K + scc*8) * 2;
    boff[r] = ((size_t)(n0+row)*K + scc*8) * 2;
    ldso[r] = (u32)(r*256 + wid*64) * 8;  // wave-uniform LDS base (shorts)
  }

  f32x4 acc[4][4];
  #pragma unroll
  for (int a = 0; a < 4; ++a)
    #pragma unroll
    for (int b = 0; b < 4; ++b) acc[a][b] = 0;

  const char* pAh = (const char*)Ah; const char* pAl = (const char*)Al;
  const char* pBh = (const char*)Bh; const char* pBl = (const char*)Bl;

  auto stage = [&](int sb, int ks){
    const size_t kb = (size_t)ks * 64;   // 32 elems * 2B
    #pragma unroll
    for (int r = 0; r < 2; ++r){
      g2l16(pAh + aoff[r] + kb, &Ash[sb][0] + ldso[r]);
      g2l16(pAl + aoff[r] + kb, &Asl[sb][0] + ldso[r]);
      g2l16(pBh + boff[r] + kb, &Bsh[sb][0] + ldso[r]);
      g2l16(pBl + boff[r] + kb, &Bsl[sb][0] + ldso[r]);
    }
  };

  const int nks = K >> 5;
  stage(0, 0);
  wait_vm0();
  __syncthreads();
  int buf = 0;
  for (int ks = 0; ks < nks; ++ks){
    if (ks + 1 < nks) stage(buf ^ 1, ks + 1);
    short8 ah[4], al[4], bh[4], bl[4];
    #pragma unroll
    for (int mt = 0; mt < 4; ++mt){
      int row = wr*64 + mt*16 + lr;
      int kcs = lg ^ ((row >> 1) & 3);
      int o = row*32 + kcs*8;
      ah[mt] = *(const short8*)(&Ash[buf][0] + o);
      al[mt] = *(const short8*)(&Asl[buf][0] + o);
    }
    #pragma unroll
    for (int nt = 0; nt < 4; ++nt){
      int row = wc*64 + nt*16 + lr;
      int kcs = lg ^ ((row >> 1) & 3);
      int o = row*32 + kcs*8;
      bh[nt] = *(const short8*)(&Bsh[buf][0] + o);
      bl[nt] = *(const short8*)(&Bsl[buf][0] + o);
    }
    __builtin_amdgcn_s_setprio(1);
    #pragma unroll
    for (int mt = 0; mt < 4; ++mt)
      #pragma unroll
      for (int nt = 0; nt < 4; ++nt){
        f32x4 c = acc[mt][nt];
        c = mfma16(ah[mt], bh[nt], c);
        c = mfma16(ah[mt], bl[nt], c);
        c = mfma16(al[mt], bh[nt], c);
        acc[mt][nt] = c;
      }
    __builtin_amdgcn_s_setprio(0);
    wait_vm0();
    __syncthreads();
    buf ^= 1;
  }

  #pragma unroll
  for (int mt = 0; mt < 4; ++mt){
    #pragma unroll
    for (int nt = 0; nt < 4; ++nt){
      const int col = n0 + wc*64 + nt*16 + lr;
      const float bv = bias[col];
      #pragma unroll
      for (int r2 = 0; r2 < 4; ++r2){
        const int row = m0 + wr*64 + mt*16 + 4*lg + r2;
        const float val = acc[mt][nt][r2] + bv;
        if constexpr (MODE == 0){
          const int which = col >> 9, rem = col & 511;
          const int hh = rem >> 6, hd = rem & 63;
          const int b_ = row >> 10, t_ = row & 1023;
          const size_t idx = ((size_t)(b_*8 + hh)*1024 + t_)*64 + hd;
          const u16 hb = f2bf(val);
          if (which == 2){
            v_h[idx] = hb;
            v_l[idx] = f2bf(val - bf2f(hb));
          } else {
            const float r1 = val - bf2f(hb);
            const u16 lb = f2bf(r1);
            const u16 mb = f2bf(r1 - bf2f(lb));
            if (which == 0){ q_h[idx]=hb; q_l[idx]=lb; q_m[idx]=mb; }
            else           { k_h[idx]=hb; k_l[idx]=lb; k_m[idx]=mb; }
          }
        } else {
          const size_t o = (size_t)row*512 + col;
          hout[o] = val + xres[o];
        }
      }
    }
  }
}

// ---------------------------------------------------------------------------
// Flash attention, causal. 64-row Q tiles, 4 waves (16 q-rows each), KV tiles 64.
// Q,K split-3 (6-pass QK^T), P,V split-2 (3-pass PV). Scores/softmax in f32.
// ---------------------------------------------------------------------------
__global__ __launch_bounds__(256) void attn_kernel(
    const u16* __restrict__ q_h, const u16* __restrict__ q_l, const u16* __restrict__ q_m,
    const u16* __restrict__ k_h, const u16* __restrict__ k_l, const u16* __restrict__ k_m,
    const u16* __restrict__ v_h, const u16* __restrict__ v_l,
    u16* __restrict__ aoh, u16* __restrict__ aol)
{
  __shared__ u16 Ksh[64*64], Ksl[64*64], Ksm[64*64];
  __shared__ u16 Vth[64*72], Vtl[64*72];
  __shared__ u16 Ph[4*16*72], Pl[4*16*72];
  const int tid = threadIdx.x, wid = tid >> 6, lane = tid & 63;
  const int lr = lane & 15, lg = lane >> 4;
  // LPT + XCD-affinity decode
  const int bfl = blockIdx.x;
  const int xcd = bfl & 7, jj_ = bfl >> 3;
  const int bh = xcd * 8 + (jj_ & 7);
  const int qt = 15 - (jj_ >> 3);
  const int q0 = qt * 64;
  const size_t base = (size_t)bh * 1024 * 64;

  short8 qfh[2], qfl[2], qfm[2];
  {
    const int qrow = q0 + wid*16 + lr;
    #pragma unroll
    for (int c = 0; c < 2; ++c){
      const size_t o = base + (size_t)qrow*64 + c*32 + lg*8;
      qfh[c] = *(const short8*)(q_h + o);
      qfl[c] = *(const short8*)(q_l + o);
      qfm[c] = *(const short8*)(q_m + o);
    }
  }
  f32x4 oacc[4];
  float m_r[4], l_r[4];
  #pragma unroll
  for (int nt = 0; nt < 4; ++nt) oacc[nt] = 0;
  #pragma unroll
  for (int r = 0; r < 4; ++r){ m_r[r] = -1e30f; l_r[r] = 0.f; }

  short8 kreg[3][2];
  short8 vreg[2][2];
  const int pp = tid & 31, d0 = (tid >> 5) * 8;

  auto load_tile = [&](int kt){
    #pragma unroll
    for (int r = 0; r < 2; ++r){
      const int i = r*256 + tid;
      const int row = i >> 3, cc = i & 7;
      const int scc = cc ^ (row & 7);       // pre-swizzled source chunk
      const size_t go = base + (size_t)(kt*64 + row)*64 + scc*8;
      kreg[0][r] = *(const short8*)(k_h + go);
      kreg[1][r] = *(const short8*)(k_l + go);
      kreg[2][r] = *(const short8*)(k_m + go);
    }
    const size_t g0 = base + (size_t)(kt*64 + 2*pp)*64 + d0;
    vreg[0][0] = *(const short8*)(v_h + g0);
    vreg[0][1] = *(const short8*)(v_h + g0 + 64);
    vreg[1][0] = *(const short8*)(v_l + g0);
    vreg[1][1] = *(const short8*)(v_l + g0 + 64);
  };

  load_tile(0);
  for (int kt = 0; kt <= qt; ++kt){
    if (kt) __syncthreads();               // prev compute done reading LDS
    #pragma unroll
    for (int r = 0; r < 2; ++r){
      const int o = (r*256 + tid) * 8;     // shorts, linear
      *(short8*)(Ksh + o) = kreg[0][r];
      *(short8*)(Ksl + o) = kreg[1][r];
      *(short8*)(Ksm + o) = kreg[2][r];
    }
    #pragma unroll
    for (int j = 0; j < 8; ++j){
      u32 ph_ = (u32)(u16)vreg[0][0][j] | ((u32)(u16)vreg[0][1][j] << 16);
      u32 pl_ = (u32)(u16)vreg[1][0][j] | ((u32)(u16)vreg[1][1][j] << 16);
      *(u32*)(Vth + (d0+j)*72 + 2*pp) = ph_;
      *(u32*)(Vtl + (d0+j)*72 + 2*pp) = pl_;
    }
    __syncthreads();
    if (kt < qt) load_tile(kt + 1);        // issue next-tile loads now
    __builtin_amdgcn_sched_barrier(0);     // pin issue point before compute

    // S = Q K^T (6-pass split-3)
    f32x4 s[4];
    #pragma unroll
    for (int nt = 0; nt < 4; ++nt) s[nt] = 0;
    __builtin_amdgcn_s_setprio(1);
    #pragma unroll
    for (int c = 0; c < 2; ++c){
      #pragma unroll
      for (int nt = 0; nt < 4; ++nt){
        const int row = nt*16 + lr;
        const int kcs = (c*4 + lg) ^ (row & 7);
        const int o = row*64 + kcs*8;
        short8 kh_ = *(const short8*)(Ksh + o);
        short8 kl_ = *(const short8*)(Ksl + o);
        short8 km_ = *(const short8*)(Ksm + o);
        f32x4 cacc = s[nt];
        cacc = mfma16(qfh[c], kh_, cacc);
        cacc = mfma16(qfh[c], kl_, cacc);
        cacc = mfma16(qfl[c], kh_, cacc);
        cacc = mfma16(qfh[c], km_, cacc);
        cacc = mfma16(qfm[c], kh_, cacc);
        cacc = mfma16(qfl[c], kl_, cacc);
        s[nt] = cacc;
      }
    }
    __builtin_amdgcn_s_setprio(0);
    // scale + causal mask
    float sc[4][4];
    const bool last = (kt == qt);
    #pragma unroll
    for (int nt = 0; nt < 4; ++nt)
      #pragma unroll
      for (int r = 0; r < 4; ++r){
        float v = s[nt][r] * 0.125f;
        if (last){
          int qa = q0 + wid*16 + 4*lg + r;
          int ka = kt*64 + nt*16 + lr;
          if (ka > qa) v = -1e30f;
        }
        sc[nt][r] = v;
      }
    // online softmax
    float pr[4][4];
    #pragma unroll
    for (int r = 0; r < 4; ++r){
      float mx = fmaxf(fmaxf(sc[0][r], sc[1][r]), fmaxf(sc[2][r], sc[3][r]));
      #pragma unroll
      for (int o2 = 8; o2; o2 >>= 1) mx = fmaxf(mx, __shfl_xor(mx, o2));
      const float nm = fmaxf(m_r[r], mx);
      const float al = __expf(m_r[r] - nm);
      float sum = 0.f;
      #pragma unroll
      for (int nt = 0; nt < 4; ++nt){
        float e_ = __expf(sc[nt][r] - nm);
        pr[nt][r] = e_;
        sum += e_;
      }
      #pragma unroll
      for (int o2 = 8; o2; o2 >>= 1) sum += __shfl_xor(sum, o2);
      l_r[r] = l_r[r]*al + sum;
      m_r[r] = nm;
      #pragma unroll
      for (int nt = 0; nt < 4; ++nt) oacc[nt][r] *= al;
    }
    // P -> per-wave LDS (split-2)
    #pragma unroll
    for (int nt = 0; nt < 4; ++nt)
      #pragma unroll
      for (int r = 0; r < 4; ++r){
        const float pv = pr[nt][r];
        const u16 hb = f2bf(pv);
        const u16 lb = f2bf(pv - bf2f(hb));
        const int o = wid*1152 + (4*lg + r)*72 + nt*16 + lr;
        Ph[o] = hb; Pl[o] = lb;
      }
    // O += P V (3-pass split-2)
    #pragma unroll
    for (int c = 0; c < 2; ++c){
      const int po = wid*1152 + lr*72 + c*32 + lg*8;
      short8 pah = *(const short8*)(Ph + po);
      short8 pal = *(const short8*)(Pl + po);
      __builtin_amdgcn_s_setprio(1);
      #pragma unroll
      for (int nt = 0; nt < 4; ++nt){
        const int vo = (nt*16 + lr)*72 + c*32 + lg*8;
        short8 vhf = *(const short8*)(Vth + vo);
        short8 vlf = *(const short8*)(Vtl + vo);
        f32x4 cacc = oacc[nt];
        cacc = mfma16(pah, vhf, cacc);
        cacc = mfma16(pah, vlf, cacc);
        cacc = mfma16(pal, vhf, cacc);
        oacc[nt] = cacc;
      }
      __builtin_amdgcn_s_setprio(0);
    }
  }

  const int b_ = bh >> 3, h_ = bh & 7;
  #pragma unroll
  for (int nt = 0; nt < 4; ++nt)
    #pragma unroll
    for (int r = 0; r < 4; ++r){
      const int qa = q0 + wid*16 + 4*lg + r;
      const float val = oacc[nt][r] / l_r[r];
      const size_t o = ((size_t)(b_*1024 + qa))*512 + h_*64 + nt*16 + lr;
      const u16 hb = f2bf(val);
      aoh[o] = hb;
      aol[o] = f2bf(val - bf2f(hb));
    }
}

// ---------------------------------------------------------------------------
// LN2 + gating: y2 bf16, logits in f32 (exact order-robust top-2). No atomics.
// ---------------------------------------------------------------------------
__global__ __launch_bounds__(256) void ln2_gate_kernel(const float* __restrict__ h,
    const float* __restrict__ g, const float* __restrict__ b,
    const float* __restrict__ Wg, u16* __restrict__ y2,
    int* __restrict__ ge, float* __restrict__ gw)
{
  const int wid = threadIdx.x >> 6, lane = threadIdx.x & 63;
  const int row = blockIdx.x * 4 + wid;
  const float* xr = h + (size_t)row * 512 + lane * 8;
  f32x4 t0 = ((const f32x4*)xr)[0], t1 = ((const f32x4*)xr)[1];
  float v[8];
  #pragma unroll
  for (int j = 0; j < 8; ++j) v[j] = (j < 4) ? t0[j] : t1[j-4];
  float s = 0.f, q = 0.f;
  #pragma unroll
  for (int j = 0; j < 8; ++j){ s += v[j]; q += v[j]*v[j]; }
  #pragma unroll
  for (int o = 32; o; o >>= 1){ s += __shfl_xor(s, o); q += __shfl_xor(q, o); }
  const float mean = s * (1.f/512.f);
  const float var  = q * (1.f/512.f) - mean*mean;
  const float rstd = rsqrtf(var + 1e-5f);
  f32x4 g0 = ((const f32x4*)(g + lane*8))[0], g1 = ((const f32x4*)(g + lane*8))[1];
  f32x4 b0 = ((const f32x4*)(b + lane*8))[0], b1 = ((const f32x4*)(b + lane*8))[1];
  float yv[8];
  short8 yb;
  #pragma unroll
  for (int j = 0; j < 8; ++j){
    float gg = (j < 4) ? g0[j] : g1[j-4];
    float bb = (j < 4) ? b0[j] : b1[j-4];
    yv[j] = (v[j]-mean)*rstd*gg + bb;
    yb[j] = (short)f2bf(yv[j]);
  }
  ((short8*)(y2 + (size_t)row*512 + lane*8))[0] = yb;

  float lgt[8];
  #pragma unroll
  for (int e = 0; e < 8; ++e) lgt[e] = 0.f;
  #pragma unroll
  for (int j = 0; j < 8; ++j){
    const float* wr_ = Wg + (size_t)(lane*8 + j) * 8;
    #pragma unroll
    for (int e = 0; e < 8; ++e) lgt[e] += yv[j] * wr_[e];
  }
  #pragma unroll
  for (int o = 32; o; o >>= 1){
    #pragma unroll
    for (int e = 0; e < 8; ++e) lgt[e] += __shfl_xor(lgt[e], o);
  }
  if (lane == 0){
    int e0 = 0; float l0 = lgt[0];
    #pragma unroll
    for (int e = 1; e < 8; ++e) if (lgt[e] > l0){ l0 = lgt[e]; e0 = e; }
    int e1 = -1; float l1 = -3e38f;
    #pragma unroll
    for (int e = 0; e < 8; ++e) if (e != e0 && lgt[e] > l1){ l1 = lgt[e]; e1 = e; }
    const float t = expf(l1 - l0);
    const float w0 = 1.f / (1.f + t);
    const float w1 = t * w0;
    ge[row*2]   = e0; ge[row*2+1] = e1;
    gw[row*2]   = w0; gw[row*2+1] = w1;
  }
}

// ---------------------------------------------------------------------------
// Routing bookkeeping. cnt layout: [0..7] counts, [8..15] offsets, [16] total,
// [17..24] cursors, [25..32] tile-prefix, [33] total tiles.
// ---------------------------------------------------------------------------
__global__ __launch_bounds__(256) void count_kernel(const int* __restrict__ ge,
                                                    int* __restrict__ cnt)
{
  const int i = blockIdx.x * 256 + threadIdx.x;   // 16384 entries
  const int lane = threadIdx.x & 63;
  const int e = ge[i];
  #pragma unroll
  for (int ex = 0; ex < 8; ++ex){
    u64 m = __ballot(e == ex);
    if (m && lane == (int)(__ffsll((long long)m) - 1))
      atomicAdd(&cnt[ex], __popcll(m));
  }
}

__global__ void offsets_kernel(int* cnt){
  if (threadIdx.x == 0){
    int o = 0, tp = 0;
    for (int e = 0; e < 8; ++e){
      cnt[8+e] = o; cnt[17+e] = o;
      cnt[25+e] = tp;
      o  += cnt[e];
      tp += (cnt[e] + 127) >> 7;
    }
    cnt[16] = o;
    cnt[33] = tp;
  }
}

__global__ __launch_bounds__(256) void scatter_kernel(const int* __restrict__ ge,
    const float* __restrict__ gw, int* __restrict__ cnt,
    int* __restrict__ rdst, float* __restrict__ rw)
{
  const int i = blockIdx.x * 256 + threadIdx.x;   // 16384 entries
  const int lane = threadIdx.x & 63;
  const int e = ge[i];
  const float w = gw[i];
  const u64 below = ((u64)1 << lane) - 1;
  int pos = -1;
  #pragma unroll
  for (int ex = 0; ex < 8; ++ex){
    u64 m = __ballot(e == ex);
    if (m){
      const int leader = (int)(__ffsll((long long)m) - 1);
      int base = 0;
      if (lane == leader) base = atomicAdd(&cnt[17 + ex], __popcll(m));
      base = __shfl(base, leader);
      if (e == ex) pos = base + __popcll(m & below);
    }
  }
  rdst[pos] = i;
  rw[pos]   = w;
}

// ---------------------------------------------------------------------------
// Grouped expert GEMM, plain bf16. 128x128 tile, BK=32, 2-phase dbuf K-loop.
// R4 band remap; R6 conflict-free swizzle; R7 launch_bounds(256,5):
// 5 blocks/CU (160KB LDS), inter-block overlap hides the per-step drain.
// MODE 2: hid[p] = gelu(y2[tok(p)] @ We1[e] + be1[e])
// MODE 3: contrib[dst(p)] = w(p) * (hid[p] @ We2[e] + be2[e])
// ---------------------------------------------------------------------------
template<int MODE, int TN, int BAND_M, int BPX>
__global__ __launch_bounds__(256, 5) void gemm_moe(
    const u16* __restrict__ A, const u16* __restrict__ Bt,
    const float* __restrict__ bias, int N, int K,
    const int* __restrict__ cntblk,
    const int* __restrict__ rdst, const float* __restrict__ rw,
    u16* __restrict__ hid, float* __restrict__ contrib)
{
  __shared__ u16 As[2][128*32], Bs[2][128*32];
  // --- band-supertile decode ---
  const int fid = blockIdx.x;
  const int xcd = fid & 7;
  const int j   = fid >> 3;
  const int bpb = BAND_M * TN;           // blocks per band
  const int bi  = j / bpb;               // local band index within this XCD
  const int r_  = j % bpb;
  const int nt_ = r_ / BAND_M;           // n-tile (slow)
  const int mi  = r_ % BAND_M;           // m-tile within band (fast)
  const int mt  = (xcd * BPX + bi) * BAND_M + mi;  // global m-tile
  if (mt >= cntblk[33]) return;
  int e = 7;
  #pragma unroll
  for (int k = 7; k >= 1; --k) if (mt < cntblk[25 + k]) e = k - 1;
  const int ce = cntblk[e];
  const int eo = cntblk[8 + e];
  const int m0 = (mt - cntblk[25 + e]) * 128;
  const int n0 = nt_ * 128;

  const int tid = threadIdx.x;
  const int wid = tid >> 6, lane = tid & 63;
  const int wr = wid >> 1, wc = wid & 1;
  const int lr = lane & 15, lg = lane >> 4;

  size_t aoff[2], boff[2];
  u32 ldso[2];
  #pragma unroll
  for (int r = 0; r < 2; ++r){
    int i = r*256 + tid;
    int row = i >> 2, cc = i & 3;
    int scc = cc ^ ((row >> 1) & 3);       // pre-swizzled source chunk (R6)
    int p = eo + m0 + row;
    const int pmax = eo + ce - 1;
    if (p > pmax) p = pmax;                // clamp tail rows to valid data
    const int arow = (MODE == 2) ? (rdst[p] >> 1) : p;
    aoff[r] = ((size_t)arow * K + scc*8) * 2;
    boff[r] = (((size_t)e * N + n0 + row) * K + scc*8) * 2;
    ldso[r] = (u32)(r*256 + wid*64) * 8;   // wave-uniform LDS base (shorts)
  }

  f32x4 acc[4][4];
  #pragma unroll
  for (int a = 0; a < 4; ++a)
    #pragma unroll
    for (int b = 0; b < 4; ++b) acc[a][b] = 0;

  const char* pA = (const char*)A;
  const char* pB = (const char*)Bt;

  auto stage = [&](int sb, int ks){
    const size_t kb = (size_t)ks * 64;     // 32 elems * 2B
    #pragma unroll
    for (int r = 0; r < 2; ++r){
      g2l16(pA + aoff[r] + kb, &As[sb][0] + ldso[r]);
      g2l16(pB + boff[r] + kb, &Bs[sb][0] + ldso[r]);
    }
  };

  const int nks = K >> 5;
  stage(0, 0);
  wait_vm0();
  __syncthreads();
  int buf = 0;
  for (int ks = 0; ks < nks; ++ks){
    if (ks + 1 < nks) stage(buf ^ 1, ks + 1);
    short8 av[4], bv[4];
    #pragma unroll
    for (int mt2 = 0; mt2 < 4; ++mt2){
      int row = wr*64 + mt2*16 + lr;
      int kcs = lg ^ ((row >> 1) & 3);
      av[mt2] = *(const short8*)(&As[buf][0] + row*32 + kcs*8);
    }
    #pragma unroll
    for (int nt2 = 0; nt2 < 4; ++nt2){
      int row = wc*64 + nt2*16 + lr;
      int kcs = lg ^ ((row >> 1) & 3);
      bv[nt2] = *(const short8*)(&Bs[buf][0] + row*32 + kcs*8);
    }
    __builtin_amdgcn_s_setprio(1);
    #pragma unroll
    for (int mt2 = 0; mt2 < 4; ++mt2)
      #pragma unroll
      for (int nt2 = 0; nt2 < 4; ++nt2)
        acc[mt2][nt2] = mfma16(av[mt2], bv[nt2], acc[mt2][nt2]);
    __builtin_amdgcn_s_setprio(0);
    wait_vm0();
    __syncthreads();
    buf ^= 1;
  }

  const float* bp = bias + (size_t)e * N;
  #pragma unroll
  for (int mt2 = 0; mt2 < 4; ++mt2){
    #pragma unroll
    for (int nt2 = 0; nt2 < 4; ++nt2){
      const int col = n0 + wc*64 + nt2*16 + lr;
      const float bv2 = bp[col];
      #pragma unroll
      for (int r2 = 0; r2 < 4; ++r2){
        const int lrow = wr*64 + mt2*16 + 4*lg + r2;
        if (m0 + lrow < ce){
          const int p = eo + m0 + lrow;
          const float val = acc[mt2][nt2][r2] + bv2;
          if constexpr (MODE == 2){
            // gelu: 0.5x(1+tanh z) == x * sigmoid(2z), exact identity
            const float gx = val;
            const float z2 = 1.5957691216057308f * (gx + 0.044715f*gx*gx*gx);
            const float gl = gx / (1.f + __expf(-z2));
            hid[(size_t)p * N + col] = f2bf(gl);
          } else {
            contrib[(size_t)rdst[p] * N + col] = val * rw[p];
          }
        }
      }
    }
  }
}

// ---------------------------------------------------------------------------
// out = h + contrib[2n] + contrib[2n+1]
// ---------------------------------------------------------------------------
__global__ __launch_bounds__(256) void final_kernel(const float* __restrict__ h,
    const float* __restrict__ contrib, float* __restrict__ out)
{
  const int i = blockIdx.x * 256 + threadIdx.x;   // 1,048,576 f32x4 groups
  const int row = i >> 7, rem = i & 127;
  const f32x4* c4 = (const f32x4*)contrib;
  f32x4 hv = ((const f32x4*)h)[i];
  f32x4 a = c4[(size_t)(row*2) * 128 + rem];
  f32x4 b = c4[(size_t)(row*2) * 128 + 128 + rem];
  ((f32x4*)out)[i] = hv + a + b;
}

// ---------------------------------------------------------------------------
extern "C" void kernel_launch(void* const* d_in, const int* in_sizes, int n_in,
                              void* d_out, int out_size, void* d_ws, size_t ws_size,
                              hipStream_t stream)
{
  (void)in_sizes; (void)n_in; (void)out_size; (void)ws_size;
  const float* x    = (const float*)d_in[0];
  const float* ln1g = (const float*)d_in[1];
  const float* ln1b = (const float*)d_in[2];
  const float* ln2g = (const float*)d_in[3];
  const float* ln2b = (const float*)d_in[4];
  const float* Wqkv = (const float*)d_in[5];
  const float* bqkv = (const float*)d_in[6];
  const float* Wo   = (const float*)d_in[7];
  const float* bo   = (const float*)d_in[8];
  const float* Wg   = (const float*)d_in[9];
  const float* We1  = (const float*)d_in[10];
  const float* be1  = (const float*)d_in[11];
  const float* We2  = (const float*)d_in[12];
  const float* be2  = (const float*)d_in[13];
  float* out = (float*)d_out;

  char* ws = (char*)d_ws;
  size_t off_ = 0;
  auto alloc = [&](size_t bytes)->char*{
    char* p = ws + off_;
    off_ = (off_ + bytes + 255) & ~(size_t)255;
    return p;
  };
  u16* wqkvTh = (u16*)alloc((size_t)1536*512*2);
  u16* wqkvTl = (u16*)alloc((size_t)1536*512*2);
  u16* woTh   = (u16*)alloc((size_t)512*512*2);
  u16* woTl   = (u16*)alloc((size_t)512*512*2);
  u16* we1T   = (u16*)alloc((size_t)8*2048*512*2);
  u16* we2T   = (u16*)alloc((size_t)8*512*2048*2);
  u16* y1h    = (u16*)alloc((size_t)8192*512*2);
  u16* y1l    = (u16*)alloc((size_t)8192*512*2);
  u16* qh_    = (u16*)alloc((size_t)8192*64*8*2);
  u16* ql_    = (u16*)alloc((size_t)8192*64*8*2);
  u16* qm_    = (u16*)alloc((size_t)8192*64*8*2);
  u16* kh_    = (u16*)alloc((size_t)8192*64*8*2);
  u16* kl_    = (u16*)alloc((size_t)8192*64*8*2);
  u16* km_    = (u16*)alloc((size_t)8192*64*8*2);
  u16* vh_    = (u16*)alloc((size_t)8192*64*8*2);
  u16* vl_    = (u16*)alloc((size_t)8192*64*8*2);
  u16* aoh    = (u16*)alloc((size_t)8192*512*2);
  u16* aol    = (u16*)alloc((size_t)8192*512*2);
  float* hbuf = (float*)alloc((size_t)8192*512*4);
  u16* y2     = (u16*)alloc((size_t)8192*512*2);
  int* ge     = (int*)alloc((size_t)8192*2*4);
  float* gw   = (float*)alloc((size_t)8192*2*4);
  int* cnt    = (int*)alloc(256);
  int* rdst   = (int*)alloc((size_t)16384*4);
  float* rw   = (float*)alloc((size_t)16384*4);
  u16* hid    = (u16*)alloc((size_t)16384*2048*2);
  float* contrib = (float*)alloc((size_t)16384*512*4);

  (void)hipMemsetAsync(cnt, 0, 256, stream);

  const dim3 tb(32, 8);
  transpose_cvt2<<<dim3(48, 16, 1), tb, 0, stream>>>(Wqkv, wqkvTh, wqkvTl, 512, 1536);
  transpose_cvt2<<<dim3(16, 16, 1), tb, 0, stream>>>(Wo,   woTh,   woTl,   512, 512);
  transpose_cvt1<<<dim3(64, 16, 8), tb, 0, stream>>>(We1, we1T, 512, 2048);
  transpose_cvt1<<<dim3(16, 64, 8), tb, 0, stream>>>(We2, we2T, 2048, 512);

  ln1_kernel<<<2048, 256, 0, stream>>>(x, ln1g, ln1b, y1h, y1l);

  gemm_split2<0><<<dim3(64, 12), 256, 0, stream>>>(
      y1h, y1l, wqkvTh, wqkvTl, bqkv, 512,
      qh_, ql_, qm_, kh_, kl_, km_, vh_, vl_, nullptr, nullptr);

  attn_kernel<<<dim3(1024), 256, 0, stream>>>(
      qh_, ql_, qm_, kh_, kl_, km_, vh_, vl_, aoh, aol);

  gemm_split2<1><<<dim3(64, 4), 256, 0, stream>>>(
      aoh, aol, woTh, woTl, bo, 512,
      nullptr, nullptr, nullptr, nullptr, nullptr, nullptr, nullptr, nullptr,
      x, hbuf);

  ln2_gate_kernel<<<2048, 256, 0, stream>>>(hbuf, ln2g, ln2b, Wg, y2, ge, gw);
  count_kernel<<<64, 256, 0, stream>>>(ge, cnt);
  offsets_kernel<<<1, 64, 0, stream>>>(cnt);
  scatter_kernel<<<64, 256, 0, stream>>>(ge, gw, cnt, rdst, rw);

  // moe2: 135 m-tiles (pad 8x3x8=192), 16 n-tiles -> grid 8*3*8*16 = 3072
  gemm_moe<2, 16, 8, 3><<<dim3(3072), 256, 0, stream>>>(
      y2, we1T, be1, 2048, 512, cnt, rdst, rw, hid, nullptr);
  // moe3: 135 m-tiles (pad 8x5x4=160), 4 n-tiles -> grid 8*5*4*4 = 640
  gemm_moe<3, 4, 4, 5><<<dim3(640), 256, 0, stream>>>(
      hid, we2T, be2, 512, 2048, cnt, rdst, rw, nullptr, contrib);

  final_kernel<<<4096, 256, 0, stream>>>(hbuf, contrib, out);
}

// Round 9
// 437.764 us; speedup vs baseline: 1.6378x; 1.6378x over previous
//
#include <hip/hip_runtime.h>

// ---------------------------------------------------------------------------
// PipelinedMoEBlock: LN1 -> QKV -> causal MHA -> Wo+res -> LN2 -> top2 MoE -> res
// B=8 T=1024 D=512 H=8 HD=64 E=8 K=2 F=2048  (Ntok = 8192)
//
// Numerics: pre-gating path uses split-bf16 compensated MFMA (~f32 accuracy)
// so the top-2 routing matches the f32 reference; experts are plain bf16.
// R1: routing atomics wave-aggregated (ballot).
// R2: 2-phase double-buffered K-loop in all MFMA GEMMs; MoE grid flattened.
// R3: attn: T14 register prefetch, LPT order, XCD head-affinity, setprio.
// R4: MoE GEMMs: XCD band-supertile remap (FETCH 169->33.6 MB) + gelu sigmoid.
// R5: MoE BK=32, 32KB LDS, launch_bounds(256,4) -> 4 blocks/CU. [100us]
// R6: conflict-free LDS swizzle kcs = lg ^ ((row>>1)&3) (4.36M conflicts -> 0).
// R7: FAILED: launch_bounds(256,5) squeezed regs to 96/wave < 48V+64A needed
//     -> acc spilled to scratch (WRITE 67->490 MB, dur 100->271us).
// R8: R5 structure + R6 swizzle, launch_bounds(256,4) — both proven pieces,
//     register budget 120 <= 128 (no spill).
// ---------------------------------------------------------------------------

typedef unsigned short u16;
typedef unsigned int   u32;
typedef unsigned long long u64;
typedef __attribute__((ext_vector_type(8))) short short8;
typedef __attribute__((ext_vector_type(4))) float f32x4;

#define DEV static __device__ __forceinline__

DEV u16 f2bf(float f){
  union { float f; u32 u; } x; x.f = f;
  return (u16)((x.u + 0x7FFFu + ((x.u >> 16) & 1u)) >> 16);
}
DEV float bf2f(u16 b){
  union { u32 u; float f; } x; x.u = ((u32)b) << 16; return x.f;
}
DEV f32x4 mfma16(short8 a, short8 b, f32x4 c){
  return __builtin_amdgcn_mfma_f32_16x16x32_bf16(a, b, c, 0, 0, 0);
}
DEV void g2l16(const void* g, void* l){
  __builtin_amdgcn_global_load_lds((const __attribute__((address_space(1))) u32*)g,
                                   (__attribute__((address_space(3))) u32*)l, 16, 0, 0);
}
DEV void wait_vm0(){ asm volatile("s_waitcnt vmcnt(0)" ::: "memory"); }

// ---------------------------------------------------------------------------
// Weight transpose + f32 -> bf16 (split-2 and single variants)
// ---------------------------------------------------------------------------
__global__ __launch_bounds__(256) void transpose_cvt2(const float* __restrict__ src,
    u16* __restrict__ dh, u16* __restrict__ dl, int R, int C)
{
  __shared__ float tile[32][33];
  const size_t zb = (size_t)blockIdx.z * R * C;
  src += zb; dh += zb; dl += zb;
  const int tx = threadIdx.x, ty = threadIdx.y;
  const int c0 = blockIdx.x * 32, r0 = blockIdx.y * 32;
  #pragma unroll
  for (int i = 0; i < 4; ++i)
    tile[ty + i*8][tx] = src[(size_t)(r0 + ty + i*8) * C + c0 + tx];
  __syncthreads();
  #pragma unroll
  for (int i = 0; i < 4; ++i){
    float v = tile[tx][ty + i*8];
    size_t o = (size_t)(c0 + ty + i*8) * R + r0 + tx;
    u16 hb = f2bf(v);
    dh[o] = hb;
    dl[o] = f2bf(v - bf2f(hb));
  }
}

__global__ __launch_bounds__(256) void transpose_cvt1(const float* __restrict__ src,
    u16* __restrict__ d, int R, int C)
{
  __shared__ float tile[32][33];
  const size_t zb = (size_t)blockIdx.z * R * C;
  src += zb; d += zb;
  const int tx = threadIdx.x, ty = threadIdx.y;
  const int c0 = blockIdx.x * 32, r0 = blockIdx.y * 32;
  #pragma unroll
  for (int i = 0; i < 4; ++i)
    tile[ty + i*8][tx] = src[(size_t)(r0 + ty + i*8) * C + c0 + tx];
  __syncthreads();
  #pragma unroll
  for (int i = 0; i < 4; ++i)
    d[(size_t)(c0 + ty + i*8) * R + r0 + tx] = f2bf(tile[tx][ty + i*8]);
}

// ---------------------------------------------------------------------------
// LN1: one wave per row, write y1 as split-2 bf16
// ---------------------------------------------------------------------------
__global__ __launch_bounds__(256) void ln1_kernel(const float* __restrict__ x,
    const float* __restrict__ g, const float* __restrict__ b,
    u16* __restrict__ yh, u16* __restrict__ yl)
{
  const int wid = threadIdx.x >> 6, lane = threadIdx.x & 63;
  const int row = blockIdx.x * 4 + wid;
  const float* xr = x + (size_t)row * 512 + lane * 8;
  f32x4 t0 = ((const f32x4*)xr)[0], t1 = ((const f32x4*)xr)[1];
  float v[8];
  #pragma unroll
  for (int j = 0; j < 8; ++j) v[j] = (j < 4) ? t0[j] : t1[j-4];
  float s = 0.f, q = 0.f;
  #pragma unroll
  for (int j = 0; j < 8; ++j){ s += v[j]; q += v[j]*v[j]; }
  #pragma unroll
  for (int o = 32; o; o >>= 1){ s += __shfl_xor(s, o); q += __shfl_xor(q, o); }
  const float mean = s * (1.f/512.f);
  const float var  = q * (1.f/512.f) - mean*mean;
  const float rstd = rsqrtf(var + 1e-5f);
  f32x4 g0 = ((const f32x4*)(g + lane*8))[0], g1 = ((const f32x4*)(g + lane*8))[1];
  f32x4 b0 = ((const f32x4*)(b + lane*8))[0], b1 = ((const f32x4*)(b + lane*8))[1];
  short8 vh, vl;
  #pragma unroll
  for (int j = 0; j < 8; ++j){
    float gg = (j < 4) ? g0[j] : g1[j-4];
    float bb = (j < 4) ? b0[j] : b1[j-4];
    float y = (v[j]-mean)*rstd*gg + bb;
    u16 hb = f2bf(y);
    vh[j] = (short)hb;
    vl[j] = (short)f2bf(y - bf2f(hb));
  }
  ((short8*)(yh + (size_t)row*512 + lane*8))[0] = vh;
  ((short8*)(yl + (size_t)row*512 + lane*8))[0] = vl;
}

// ---------------------------------------------------------------------------
// Split-2 GEMM: C = (Ah+Al) @ (Bh+Bl)^T, 3 MFMA passes. 128x128 tile, BK=32.
// 2-phase double-buffered K-loop. R6 swizzle: kcs = lg ^ ((row>>1)&3).
// ---------------------------------------------------------------------------
template<int MODE>
__global__ __launch_bounds__(256) void gemm_split2(
    const u16* __restrict__ Ah, const u16* __restrict__ Al,
    const u16* __restrict__ Bh, const u16* __restrict__ Bl,
    const float* __restrict__ bias, int K,
    u16* __restrict__ q_h, u16* __restrict__ q_l, u16* __restrict__ q_m,
    u16* __restrict__ k_h, u16* __restrict__ k_l, u16* __restrict__ k_m,
    u16* __restrict__ v_h, u16* __restrict__ v_l,
    const float* __restrict__ xres, float* __restrict__ hout)
{
  __shared__ u16 Ash[2][128*32], Asl[2][128*32], Bsh[2][128*32], Bsl[2][128*32];
  const int tid = threadIdx.x;
  const int wid = tid >> 6, lane = tid & 63;
  const int wr = wid >> 1, wc = wid & 1;
  const int lr = lane & 15, lg = lane >> 4;
  const int m0 = blockIdx.x * 128, n0 = blockIdx.y * 128;

  size_t aoff[2], boff[2];
  u32 ldso[2];
  #pragma unroll
  for (int r = 0; r < 2; ++r){
    int i = r*256 + tid;
    int row = i >> 2, cc = i & 3;
    int scc = cc ^ ((row >> 1) & 3);      // pre-swizzled source chunk (R6)
    aoff[r] = ((size_t)(m0+row)*K + scc*8) * 2;
    boff[r] = ((size_t)(n0+row)*K + scc*8) * 2;
    ldso[r] = (u32)(r*256 + wid*64) * 8;  // wave-uniform LDS base (shorts)
  }

  f32x4 acc[4][4];
  #pragma unroll
  for (int a = 0; a < 4; ++a)
    #pragma unroll
    for (int b = 0; b < 4; ++b) acc[a][b] = 0;

  const char* pAh = (const char*)Ah; const char* pAl = (const char*)Al;
  const char* pBh = (const char*)Bh; const char* pBl = (const char*)Bl;

  auto stage = [&](int sb, int ks){
    const size_t kb = (size_t)ks * 64;   // 32 elems * 2B
    #pragma unroll
    for (int r = 0; r < 2; ++r){
      g2l16(pAh + aoff[r] + kb, &Ash[sb][0] + ldso[r]);
      g2l16(pAl + aoff[r] + kb, &Asl[sb][0] + ldso[r]);
      g2l16(pBh + boff[r] + kb, &Bsh[sb][0] + ldso[r]);
      g2l16(pBl + boff[r] + kb, &Bsl[sb][0] + ldso[r]);
    }
  };

  const int nks = K >> 5;
  stage(0, 0);
  wait_vm0();
  __syncthreads();
  int buf = 0;
  for (int ks = 0; ks < nks; ++ks){
    if (ks + 1 < nks) stage(buf ^ 1, ks + 1);
    short8 ah[4], al[4], bh[4], bl[4];
    #pragma unroll
    for (int mt = 0; mt < 4; ++mt){
      int row = wr*64 + mt*16 + lr;
      int kcs = lg ^ ((row >> 1) & 3);
      int o = row*32 + kcs*8;
      ah[mt] = *(const short8*)(&Ash[buf][0] + o);
      al[mt] = *(const short8*)(&Asl[buf][0] + o);
    }
    #pragma unroll
    for (int nt = 0; nt < 4; ++nt){
      int row = wc*64 + nt*16 + lr;
      int kcs = lg ^ ((row >> 1) & 3);
      int o = row*32 + kcs*8;
      bh[nt] = *(const short8*)(&Bsh[buf][0] + o);
      bl[nt] = *(const short8*)(&Bsl[buf][0] + o);
    }
    __builtin_amdgcn_s_setprio(1);
    #pragma unroll
    for (int mt = 0; mt < 4; ++mt)
      #pragma unroll
      for (int nt = 0; nt < 4; ++nt){
        f32x4 c = acc[mt][nt];
        c = mfma16(ah[mt], bh[nt], c);
        c = mfma16(ah[mt], bl[nt], c);
        c = mfma16(al[mt], bh[nt], c);
        acc[mt][nt] = c;
      }
    __builtin_amdgcn_s_setprio(0);
    wait_vm0();
    __syncthreads();
    buf ^= 1;
  }

  #pragma unroll
  for (int mt = 0; mt < 4; ++mt){
    #pragma unroll
    for (int nt = 0; nt < 4; ++nt){
      const int col = n0 + wc*64 + nt*16 + lr;
      const float bv = bias[col];
      #pragma unroll
      for (int r2 = 0; r2 < 4; ++r2){
        const int row = m0 + wr*64 + mt*16 + 4*lg + r2;
        const float val = acc[mt][nt][r2] + bv;
        if constexpr (MODE == 0){
          const int which = col >> 9, rem = col & 511;
          const int hh = rem >> 6, hd = rem & 63;
          const int b_ = row >> 10, t_ = row & 1023;
          const size_t idx = ((size_t)(b_*8 + hh)*1024 + t_)*64 + hd;
          const u16 hb = f2bf(val);
          if (which == 2){
            v_h[idx] = hb;
            v_l[idx] = f2bf(val - bf2f(hb));
          } else {
            const float r1 = val - bf2f(hb);
            const u16 lb = f2bf(r1);
            const u16 mb = f2bf(r1 - bf2f(lb));
            if (which == 0){ q_h[idx]=hb; q_l[idx]=lb; q_m[idx]=mb; }
            else           { k_h[idx]=hb; k_l[idx]=lb; k_m[idx]=mb; }
          }
        } else {
          const size_t o = (size_t)row*512 + col;
          hout[o] = val + xres[o];
        }
      }
    }
  }
}

// ---------------------------------------------------------------------------
// Flash attention, causal. 64-row Q tiles, 4 waves (16 q-rows each), KV tiles 64.
// Q,K split-3 (6-pass QK^T), P,V split-2 (3-pass PV). Scores/softmax in f32.
// ---------------------------------------------------------------------------
__global__ __launch_bounds__(256) void attn_kernel(
    const u16* __restrict__ q_h, const u16* __restrict__ q_l, const u16* __restrict__ q_m,
    const u16* __restrict__ k_h, const u16* __restrict__ k_l, const u16* __restrict__ k_m,
    const u16* __restrict__ v_h, const u16* __restrict__ v_l,
    u16* __restrict__ aoh, u16* __restrict__ aol)
{
  __shared__ u16 Ksh[64*64], Ksl[64*64], Ksm[64*64];
  __shared__ u16 Vth[64*72], Vtl[64*72];
  __shared__ u16 Ph[4*16*72], Pl[4*16*72];
  const int tid = threadIdx.x, wid = tid >> 6, lane = tid & 63;
  const int lr = lane & 15, lg = lane >> 4;
  // LPT + XCD-affinity decode
  const int bfl = blockIdx.x;
  const int xcd = bfl & 7, jj_ = bfl >> 3;
  const int bh = xcd * 8 + (jj_ & 7);
  const int qt = 15 - (jj_ >> 3);
  const int q0 = qt * 64;
  const size_t base = (size_t)bh * 1024 * 64;

  short8 qfh[2], qfl[2], qfm[2];
  {
    const int qrow = q0 + wid*16 + lr;
    #pragma unroll
    for (int c = 0; c < 2; ++c){
      const size_t o = base + (size_t)qrow*64 + c*32 + lg*8;
      qfh[c] = *(const short8*)(q_h + o);
      qfl[c] = *(const short8*)(q_l + o);
      qfm[c] = *(const short8*)(q_m + o);
    }
  }
  f32x4 oacc[4];
  float m_r[4], l_r[4];
  #pragma unroll
  for (int nt = 0; nt < 4; ++nt) oacc[nt] = 0;
  #pragma unroll
  for (int r = 0; r < 4; ++r){ m_r[r] = -1e30f; l_r[r] = 0.f; }

  short8 kreg[3][2];
  short8 vreg[2][2];
  const int pp = tid & 31, d0 = (tid >> 5) * 8;

  auto load_tile = [&](int kt){
    #pragma unroll
    for (int r = 0; r < 2; ++r){
      const int i = r*256 + tid;
      const int row = i >> 3, cc = i & 7;
      const int scc = cc ^ (row & 7);       // pre-swizzled source chunk
      const size_t go = base + (size_t)(kt*64 + row)*64 + scc*8;
      kreg[0][r] = *(const short8*)(k_h + go);
      kreg[1][r] = *(const short8*)(k_l + go);
      kreg[2][r] = *(const short8*)(k_m + go);
    }
    const size_t g0 = base + (size_t)(kt*64 + 2*pp)*64 + d0;
    vreg[0][0] = *(const short8*)(v_h + g0);
    vreg[0][1] = *(const short8*)(v_h + g0 + 64);
    vreg[1][0] = *(const short8*)(v_l + g0);
    vreg[1][1] = *(const short8*)(v_l + g0 + 64);
  };

  load_tile(0);
  for (int kt = 0; kt <= qt; ++kt){
    if (kt) __syncthreads();               // prev compute done reading LDS
    #pragma unroll
    for (int r = 0; r < 2; ++r){
      const int o = (r*256 + tid) * 8;     // shorts, linear
      *(short8*)(Ksh + o) = kreg[0][r];
      *(short8*)(Ksl + o) = kreg[1][r];
      *(short8*)(Ksm + o) = kreg[2][r];
    }
    #pragma unroll
    for (int j = 0; j < 8; ++j){
      u32 ph_ = (u32)(u16)vreg[0][0][j] | ((u32)(u16)vreg[0][1][j] << 16);
      u32 pl_ = (u32)(u16)vreg[1][0][j] | ((u32)(u16)vreg[1][1][j] << 16);
      *(u32*)(Vth + (d0+j)*72 + 2*pp) = ph_;
      *(u32*)(Vtl + (d0+j)*72 + 2*pp) = pl_;
    }
    __syncthreads();
    if (kt < qt) load_tile(kt + 1);        // issue next-tile loads now
    __builtin_amdgcn_sched_barrier(0);     // pin issue point before compute

    // S = Q K^T (6-pass split-3)
    f32x4 s[4];
    #pragma unroll
    for (int nt = 0; nt < 4; ++nt) s[nt] = 0;
    __builtin_amdgcn_s_setprio(1);
    #pragma unroll
    for (int c = 0; c < 2; ++c){
      #pragma unroll
      for (int nt = 0; nt < 4; ++nt){
        const int row = nt*16 + lr;
        const int kcs = (c*4 + lg) ^ (row & 7);
        const int o = row*64 + kcs*8;
        short8 kh_ = *(const short8*)(Ksh + o);
        short8 kl_ = *(const short8*)(Ksl + o);
        short8 km_ = *(const short8*)(Ksm + o);
        f32x4 cacc = s[nt];
        cacc = mfma16(qfh[c], kh_, cacc);
        cacc = mfma16(qfh[c], kl_, cacc);
        cacc = mfma16(qfl[c], kh_, cacc);
        cacc = mfma16(qfh[c], km_, cacc);
        cacc = mfma16(qfm[c], kh_, cacc);
        cacc = mfma16(qfl[c], kl_, cacc);
        s[nt] = cacc;
      }
    }
    __builtin_amdgcn_s_setprio(0);
    // scale + causal mask
    float sc[4][4];
    const bool last = (kt == qt);
    #pragma unroll
    for (int nt = 0; nt < 4; ++nt)
      #pragma unroll
      for (int r = 0; r < 4; ++r){
        float v = s[nt][r] * 0.125f;
        if (last){
          int qa = q0 + wid*16 + 4*lg + r;
          int ka = kt*64 + nt*16 + lr;
          if (ka > qa) v = -1e30f;
        }
        sc[nt][r] = v;
      }
    // online softmax
    float pr[4][4];
    #pragma unroll
    for (int r = 0; r < 4; ++r){
      float mx = fmaxf(fmaxf(sc[0][r], sc[1][r]), fmaxf(sc[2][r], sc[3][r]));
      #pragma unroll
      for (int o2 = 8; o2; o2 >>= 1) mx = fmaxf(mx, __shfl_xor(mx, o2));
      const float nm = fmaxf(m_r[r], mx);
      const float al = __expf(m_r[r] - nm);
      float sum = 0.f;
      #pragma unroll
      for (int nt = 0; nt < 4; ++nt){
        float e_ = __expf(sc[nt][r] - nm);
        pr[nt][r] = e_;
        sum += e_;
      }
      #pragma unroll
      for (int o2 = 8; o2; o2 >>= 1) sum += __shfl_xor(sum, o2);
      l_r[r] = l_r[r]*al + sum;
      m_r[r] = nm;
      #pragma unroll
      for (int nt = 0; nt < 4; ++nt) oacc[nt][r] *= al;
    }
    // P -> per-wave LDS (split-2)
    #pragma unroll
    for (int nt = 0; nt < 4; ++nt)
      #pragma unroll
      for (int r = 0; r < 4; ++r){
        const float pv = pr[nt][r];
        const u16 hb = f2bf(pv);
        const u16 lb = f2bf(pv - bf2f(hb));
        const int o = wid*1152 + (4*lg + r)*72 + nt*16 + lr;
        Ph[o] = hb; Pl[o] = lb;
      }
    // O += P V (3-pass split-2)
    #pragma unroll
    for (int c = 0; c < 2; ++c){
      const int po = wid*1152 + lr*72 + c*32 + lg*8;
      short8 pah = *(const short8*)(Ph + po);
      short8 pal = *(const short8*)(Pl + po);
      __builtin_amdgcn_s_setprio(1);
      #pragma unroll
      for (int nt = 0; nt < 4; ++nt){
        const int vo = (nt*16 + lr)*72 + c*32 + lg*8;
        short8 vhf = *(const short8*)(Vth + vo);
        short8 vlf = *(const short8*)(Vtl + vo);
        f32x4 cacc = oacc[nt];
        cacc = mfma16(pah, vhf, cacc);
        cacc = mfma16(pah, vlf, cacc);
        cacc = mfma16(pal, vhf, cacc);
        oacc[nt] = cacc;
      }
      __builtin_amdgcn_s_setprio(0);
    }
  }

  const int b_ = bh >> 3, h_ = bh & 7;
  #pragma unroll
  for (int nt = 0; nt < 4; ++nt)
    #pragma unroll
    for (int r = 0; r < 4; ++r){
      const int qa = q0 + wid*16 + 4*lg + r;
      const float val = oacc[nt][r] / l_r[r];
      const size_t o = ((size_t)(b_*1024 + qa))*512 + h_*64 + nt*16 + lr;
      const u16 hb = f2bf(val);
      aoh[o] = hb;
      aol[o] = f2bf(val - bf2f(hb));
    }
}

// ---------------------------------------------------------------------------
// LN2 + gating: y2 bf16, logits in f32 (exact order-robust top-2). No atomics.
// ---------------------------------------------------------------------------
__global__ __launch_bounds__(256) void ln2_gate_kernel(const float* __restrict__ h,
    const float* __restrict__ g, const float* __restrict__ b,
    const float* __restrict__ Wg, u16* __restrict__ y2,
    int* __restrict__ ge, float* __restrict__ gw)
{
  const int wid = threadIdx.x >> 6, lane = threadIdx.x & 63;
  const int row = blockIdx.x * 4 + wid;
  const float* xr = h + (size_t)row * 512 + lane * 8;
  f32x4 t0 = ((const f32x4*)xr)[0], t1 = ((const f32x4*)xr)[1];
  float v[8];
  #pragma unroll
  for (int j = 0; j < 8; ++j) v[j] = (j < 4) ? t0[j] : t1[j-4];
  float s = 0.f, q = 0.f;
  #pragma unroll
  for (int j = 0; j < 8; ++j){ s += v[j]; q += v[j]*v[j]; }
  #pragma unroll
  for (int o = 32; o; o >>= 1){ s += __shfl_xor(s, o); q += __shfl_xor(q, o); }
  const float mean = s * (1.f/512.f);
  const float var  = q * (1.f/512.f) - mean*mean;
  const float rstd = rsqrtf(var + 1e-5f);
  f32x4 g0 = ((const f32x4*)(g + lane*8))[0], g1 = ((const f32x4*)(g + lane*8))[1];
  f32x4 b0 = ((const f32x4*)(b + lane*8))[0], b1 = ((const f32x4*)(b + lane*8))[1];
  float yv[8];
  short8 yb;
  #pragma unroll
  for (int j = 0; j < 8; ++j){
    float gg = (j < 4) ? g0[j] : g1[j-4];
    float bb = (j < 4) ? b0[j] : b1[j-4];
    yv[j] = (v[j]-mean)*rstd*gg + bb;
    yb[j] = (short)f2bf(yv[j]);
  }
  ((short8*)(y2 + (size_t)row*512 + lane*8))[0] = yb;

  float lgt[8];
  #pragma unroll
  for (int e = 0; e < 8; ++e) lgt[e] = 0.f;
  #pragma unroll
  for (int j = 0; j < 8; ++j){
    const float* wr_ = Wg + (size_t)(lane*8 + j) * 8;
    #pragma unroll
    for (int e = 0; e < 8; ++e) lgt[e] += yv[j] * wr_[e];
  }
  #pragma unroll
  for (int o = 32; o; o >>= 1){
    #pragma unroll
    for (int e = 0; e < 8; ++e) lgt[e] += __shfl_xor(lgt[e], o);
  }
  if (lane == 0){
    int e0 = 0; float l0 = lgt[0];
    #pragma unroll
    for (int e = 1; e < 8; ++e) if (lgt[e] > l0){ l0 = lgt[e]; e0 = e; }
    int e1 = -1; float l1 = -3e38f;
    #pragma unroll
    for (int e = 0; e < 8; ++e) if (e != e0 && lgt[e] > l1){ l1 = lgt[e]; e1 = e; }
    const float t = expf(l1 - l0);
    const float w0 = 1.f / (1.f + t);
    const float w1 = t * w0;
    ge[row*2]   = e0; ge[row*2+1] = e1;
    gw[row*2]   = w0; gw[row*2+1] = w1;
  }
}

// ---------------------------------------------------------------------------
// Routing bookkeeping. cnt layout: [0..7] counts, [8..15] offsets, [16] total,
// [17..24] cursors, [25..32] tile-prefix, [33] total tiles.
// ---------------------------------------------------------------------------
__global__ __launch_bounds__(256) void count_kernel(const int* __restrict__ ge,
                                                    int* __restrict__ cnt)
{
  const int i = blockIdx.x * 256 + threadIdx.x;   // 16384 entries
  const int lane = threadIdx.x & 63;
  const int e = ge[i];
  #pragma unroll
  for (int ex = 0; ex < 8; ++ex){
    u64 m = __ballot(e == ex);
    if (m && lane == (int)(__ffsll((long long)m) - 1))
      atomicAdd(&cnt[ex], __popcll(m));
  }
}

__global__ void offsets_kernel(int* cnt){
  if (threadIdx.x == 0){
    int o = 0, tp = 0;
    for (int e = 0; e < 8; ++e){
      cnt[8+e] = o; cnt[17+e] = o;
      cnt[25+e] = tp;
      o  += cnt[e];
      tp += (cnt[e] + 127) >> 7;
    }
    cnt[16] = o;
    cnt[33] = tp;
  }
}

__global__ __launch_bounds__(256) void scatter_kernel(const int* __restrict__ ge,
    const float* __restrict__ gw, int* __restrict__ cnt,
    int* __restrict__ rdst, float* __restrict__ rw)
{
  const int i = blockIdx.x * 256 + threadIdx.x;   // 16384 entries
  const int lane = threadIdx.x & 63;
  const int e = ge[i];
  const float w = gw[i];
  const u64 below = ((u64)1 << lane) - 1;
  int pos = -1;
  #pragma unroll
  for (int ex = 0; ex < 8; ++ex){
    u64 m = __ballot(e == ex);
    if (m){
      const int leader = (int)(__ffsll((long long)m) - 1);
      int base = 0;
      if (lane == leader) base = atomicAdd(&cnt[17 + ex], __popcll(m));
      base = __shfl(base, leader);
      if (e == ex) pos = base + __popcll(m & below);
    }
  }
  rdst[pos] = i;
  rw[pos]   = w;
}

// ---------------------------------------------------------------------------
// Grouped expert GEMM, plain bf16. 128x128 tile, BK=32, 2-phase dbuf K-loop.
// R4 band remap; R6 conflict-free swizzle; R8 launch_bounds(256,4):
// 4 blocks/CU (128KB LDS), regs 56V+64A=120 <= 128/wave (no spill).
// MODE 2: hid[p] = gelu(y2[tok(p)] @ We1[e] + be1[e])
// MODE 3: contrib[dst(p)] = w(p) * (hid[p] @ We2[e] + be2[e])
// ---------------------------------------------------------------------------
template<int MODE, int TN, int BAND_M, int BPX>
__global__ __launch_bounds__(256, 4) void gemm_moe(
    const u16* __restrict__ A, const u16* __restrict__ Bt,
    const float* __restrict__ bias, int N, int K,
    const int* __restrict__ cntblk,
    const int* __restrict__ rdst, const float* __restrict__ rw,
    u16* __restrict__ hid, float* __restrict__ contrib)
{
  __shared__ u16 As[2][128*32], Bs[2][128*32];
  // --- band-supertile decode ---
  const int fid = blockIdx.x;
  const int xcd = fid & 7;
  const int j   = fid >> 3;
  const int bpb = BAND_M * TN;           // blocks per band
  const int bi  = j / bpb;               // local band index within this XCD
  const int r_  = j % bpb;
  const int nt_ = r_ / BAND_M;           // n-tile (slow)
  const int mi  = r_ % BAND_M;           // m-tile within band (fast)
  const int mt  = (xcd * BPX + bi) * BAND_M + mi;  // global m-tile
  if (mt >= cntblk[33]) return;
  int e = 7;
  #pragma unroll
  for (int k = 7; k >= 1; --k) if (mt < cntblk[25 + k]) e = k - 1;
  const int ce = cntblk[e];
  const int eo = cntblk[8 + e];
  const int m0 = (mt - cntblk[25 + e]) * 128;
  const int n0 = nt_ * 128;

  const int tid = threadIdx.x;
  const int wid = tid >> 6, lane = tid & 63;
  const int wr = wid >> 1, wc = wid & 1;
  const int lr = lane & 15, lg = lane >> 4;

  size_t aoff[2], boff[2];
  u32 ldso[2];
  #pragma unroll
  for (int r = 0; r < 2; ++r){
    int i = r*256 + tid;
    int row = i >> 2, cc = i & 3;
    int scc = cc ^ ((row >> 1) & 3);       // pre-swizzled source chunk (R6)
    int p = eo + m0 + row;
    const int pmax = eo + ce - 1;
    if (p > pmax) p = pmax;                // clamp tail rows to valid data
    const int arow = (MODE == 2) ? (rdst[p] >> 1) : p;
    aoff[r] = ((size_t)arow * K + scc*8) * 2;
    boff[r] = (((size_t)e * N + n0 + row) * K + scc*8) * 2;
    ldso[r] = (u32)(r*256 + wid*64) * 8;   // wave-uniform LDS base (shorts)
  }

  f32x4 acc[4][4];
  #pragma unroll
  for (int a = 0; a < 4; ++a)
    #pragma unroll
    for (int b = 0; b < 4; ++b) acc[a][b] = 0;

  const char* pA = (const char*)A;
  const char* pB = (const char*)Bt;

  auto stage = [&](int sb, int ks){
    const size_t kb = (size_t)ks * 64;     // 32 elems * 2B
    #pragma unroll
    for (int r = 0; r < 2; ++r){
      g2l16(pA + aoff[r] + kb, &As[sb][0] + ldso[r]);
      g2l16(pB + boff[r] + kb, &Bs[sb][0] + ldso[r]);
    }
  };

  const int nks = K >> 5;
  stage(0, 0);
  wait_vm0();
  __syncthreads();
  int buf = 0;
  for (int ks = 0; ks < nks; ++ks){
    if (ks + 1 < nks) stage(buf ^ 1, ks + 1);
    short8 av[4], bv[4];
    #pragma unroll
    for (int mt2 = 0; mt2 < 4; ++mt2){
      int row = wr*64 + mt2*16 + lr;
      int kcs = lg ^ ((row >> 1) & 3);
      av[mt2] = *(const short8*)(&As[buf][0] + row*32 + kcs*8);
    }
    #pragma unroll
    for (int nt2 = 0; nt2 < 4; ++nt2){
      int row = wc*64 + nt2*16 + lr;
      int kcs = lg ^ ((row >> 1) & 3);
      bv[nt2] = *(const short8*)(&Bs[buf][0] + row*32 + kcs*8);
    }
    __builtin_amdgcn_s_setprio(1);
    #pragma unroll
    for (int mt2 = 0; mt2 < 4; ++mt2)
      #pragma unroll
      for (int nt2 = 0; nt2 < 4; ++nt2)
        acc[mt2][nt2] = mfma16(av[mt2], bv[nt2], acc[mt2][nt2]);
    __builtin_amdgcn_s_setprio(0);
    wait_vm0();
    __syncthreads();
    buf ^= 1;
  }

  const float* bp = bias + (size_t)e * N;
  #pragma unroll
  for (int mt2 = 0; mt2 < 4; ++mt2){
    #pragma unroll
    for (int nt2 = 0; nt2 < 4; ++nt2){
      const int col = n0 + wc*64 + nt2*16 + lr;
      const float bv2 = bp[col];
      #pragma unroll
      for (int r2 = 0; r2 < 4; ++r2){
        const int lrow = wr*64 + mt2*16 + 4*lg + r2;
        if (m0 + lrow < ce){
          const int p = eo + m0 + lrow;
          const float val = acc[mt2][nt2][r2] + bv2;
          if constexpr (MODE == 2){
            // gelu: 0.5x(1+tanh z) == x * sigmoid(2z), exact identity
            const float gx = val;
            const float z2 = 1.5957691216057308f * (gx + 0.044715f*gx*gx*gx);
            const float gl = gx / (1.f + __expf(-z2));
            hid[(size_t)p * N + col] = f2bf(gl);
          } else {
            contrib[(size_t)rdst[p] * N + col] = val * rw[p];
          }
        }
      }
    }
  }
}

// ---------------------------------------------------------------------------
// out = h + contrib[2n] + contrib[2n+1]
// ---------------------------------------------------------------------------
__global__ __launch_bounds__(256) void final_kernel(const float* __restrict__ h,
    const float* __restrict__ contrib, float* __restrict__ out)
{
  const int i = blockIdx.x * 256 + threadIdx.x;   // 1,048,576 f32x4 groups
  const int row = i >> 7, rem = i & 127;
  const f32x4* c4 = (const f32x4*)contrib;
  f32x4 hv = ((const f32x4*)h)[i];
  f32x4 a = c4[(size_t)(row*2) * 128 + rem];
  f32x4 b = c4[(size_t)(row*2) * 128 + 128 + rem];
  ((f32x4*)out)[i] = hv + a + b;
}

// ---------------------------------------------------------------------------
extern "C" void kernel_launch(void* const* d_in, const int* in_sizes, int n_in,
                              void* d_out, int out_size, void* d_ws, size_t ws_size,
                              hipStream_t stream)
{
  (void)in_sizes; (void)n_in; (void)out_size; (void)ws_size;
  const float* x    = (const float*)d_in[0];
  const float* ln1g = (const float*)d_in[1];
  const float* ln1b = (const float*)d_in[2];
  const float* ln2g = (const float*)d_in[3];
  const float* ln2b = (const float*)d_in[4];
  const float* Wqkv = (const float*)d_in[5];
  const float* bqkv = (const float*)d_in[6];
  const float* Wo   = (const float*)d_in[7];
  const float* bo   = (const float*)d_in[8];
  const float* Wg   = (const float*)d_in[9];
  const float* We1  = (const float*)d_in[10];
  const float* be1  = (const float*)d_in[11];
  const float* We2  = (const float*)d_in[12];
  const float* be2  = (const float*)d_in[13];
  float* out = (float*)d_out;

  char* ws = (char*)d_ws;
  size_t off_ = 0;
  auto alloc = [&](size_t bytes)->char*{
    char* p = ws + off_;
    off_ = (off_ + bytes + 255) & ~(size_t)255;
    return p;
  };
  u16* wqkvTh = (u16*)alloc((size_t)1536*512*2);
  u16* wqkvTl = (u16*)alloc((size_t)1536*512*2);
  u16* woTh   = (u16*)alloc((size_t)512*512*2);
  u16* woTl   = (u16*)alloc((size_t)512*512*2);
  u16* we1T   = (u16*)alloc((size_t)8*2048*512*2);
  u16* we2T   = (u16*)alloc((size_t)8*512*2048*2);
  u16* y1h    = (u16*)alloc((size_t)8192*512*2);
  u16* y1l    = (u16*)alloc((size_t)8192*512*2);
  u16* qh_    = (u16*)alloc((size_t)8192*64*8*2);
  u16* ql_    = (u16*)alloc((size_t)8192*64*8*2);
  u16* qm_    = (u16*)alloc((size_t)8192*64*8*2);
  u16* kh_    = (u16*)alloc((size_t)8192*64*8*2);
  u16* kl_    = (u16*)alloc((size_t)8192*64*8*2);
  u16* km_    = (u16*)alloc((size_t)8192*64*8*2);
  u16* vh_    = (u16*)alloc((size_t)8192*64*8*2);
  u16* vl_    = (u16*)alloc((size_t)8192*64*8*2);
  u16* aoh    = (u16*)alloc((size_t)8192*512*2);
  u16* aol    = (u16*)alloc((size_t)8192*512*2);
  float* hbuf = (float*)alloc((size_t)8192*512*4);
  u16* y2     = (u16*)alloc((size_t)8192*512*2);
  int* ge     = (int*)alloc((size_t)8192*2*4);
  float* gw   = (float*)alloc((size_t)8192*2*4);
  int* cnt    = (int*)alloc(256);
  int* rdst   = (int*)alloc((size_t)16384*4);
  float* rw   = (float*)alloc((size_t)16384*4);
  u16* hid    = (u16*)alloc((size_t)16384*2048*2);
  float* contrib = (float*)alloc((size_t)16384*512*4);

  (void)hipMemsetAsync(cnt, 0, 256, stream);

  const dim3 tb(32, 8);
  transpose_cvt2<<<dim3(48, 16, 1), tb, 0, stream>>>(Wqkv, wqkvTh, wqkvTl, 512, 1536);
  transpose_cvt2<<<dim3(16, 16, 1), tb, 0, stream>>>(Wo,   woTh,   woTl,   512, 512);
  transpose_cvt1<<<dim3(64, 16, 8), tb, 0, stream>>>(We1, we1T, 512, 2048);
  transpose_cvt1<<<dim3(16, 64, 8), tb, 0, stream>>>(We2, we2T, 2048, 512);

  ln1_kernel<<<2048, 256, 0, stream>>>(x, ln1g, ln1b, y1h, y1l);

  gemm_split2<0><<<dim3(64, 12), 256, 0, stream>>>(
      y1h, y1l, wqkvTh, wqkvTl, bqkv, 512,
      qh_, ql_, qm_, kh_, kl_, km_, vh_, vl_, nullptr, nullptr);

  attn_kernel<<<dim3(1024), 256, 0, stream>>>(
      qh_, ql_, qm_, kh_, kl_, km_, vh_, vl_, aoh, aol);

  gemm_split2<1><<<dim3(64, 4), 256, 0, stream>>>(
      aoh, aol, woTh, woTl, bo, 512,
      nullptr, nullptr, nullptr, nullptr, nullptr, nullptr, nullptr, nullptr,
      x, hbuf);

  ln2_gate_kernel<<<2048, 256, 0, stream>>>(hbuf, ln2g, ln2b, Wg, y2, ge, gw);
  count_kernel<<<64, 256, 0, stream>>>(ge, cnt);
  offsets_kernel<<<1, 64, 0, stream>>>(cnt);
  scatter_kernel<<<64, 256, 0, stream>>>(ge, gw, cnt, rdst, rw);

  // moe2: 135 m-tiles (pad 8x3x8=192), 16 n-tiles -> grid 8*3*8*16 = 3072
  gemm_moe<2, 16, 8, 3><<<dim3(3072), 256, 0, stream>>>(
      y2, we1T, be1, 2048, 512, cnt, rdst, rw, hid, nullptr);
  // moe3: 135 m-tiles (pad 8x5x4=160), 4 n-tiles -> grid 8*5*4*4 = 640
  gemm_moe<3, 4, 4, 5><<<dim3(640), 256, 0, stream>>>(
      hid, we2T, be2, 512, 2048, cnt, rdst, rw, nullptr, contrib);

  final_kernel<<<4096, 256, 0, stream>>>(hbuf, contrib, out);
}

// Round 10
// 421.898 us; speedup vs baseline: 1.6994x; 1.0376x over previous
//
#include <hip/hip_runtime.h>

// ---------------------------------------------------------------------------
// PipelinedMoEBlock: LN1 -> QKV -> causal MHA -> Wo+res -> LN2 -> top2 MoE -> res
// B=8 T=1024 D=512 H=8 HD=64 E=8 K=2 F=2048  (Ntok = 8192)
//
// Numerics: pre-gating path uses split-bf16 compensated MFMA (~f32 accuracy)
// so the top-2 routing matches the f32 reference; experts are plain bf16.
// R1: routing atomics wave-aggregated (ballot).
// R2: 2-phase double-buffered K-loop in all MFMA GEMMs; MoE grid flattened.
// R3: attn: T14 register prefetch, LPT order, XCD head-affinity, setprio.
// R4: MoE GEMMs: XCD band-supertile remap + gelu sigmoid.
// R5: MoE BK=32, 32KB LDS, launch_bounds(256,4) -> 4 blocks/CU. [100us]
// R6: conflict-free LDS swizzle kcs = lg ^ ((row>>1)&3) (4.36M -> 0; neutral).
// R7: FAILED: launch_bounds(256,5) -> acc spill (WRITE 490 MB, 271us).
// R8: R5 + R6 swizzle + (256,4). [moe2 102us, MfmaUtil 13%]
// R9: R4's contiguous band->XCD mapping left XCDs 6,7 with ZERO real m-tiles
//     in moe2 (135 tiles, ranges [24*xcd,24*xcd+24)) and XCD 7 idle in moe3 —
//     blocks are HW-pinned to fid%8, so 25-33% makespan tax. Fix: round-robin
//     bands (band = bi*8+xcd, BAND_M=2): every XCD gets 8-9 bands.
// ---------------------------------------------------------------------------

typedef unsigned short u16;
typedef unsigned int   u32;
typedef unsigned long long u64;
typedef __attribute__((ext_vector_type(8))) short short8;
typedef __attribute__((ext_vector_type(4))) float f32x4;

#define DEV static __device__ __forceinline__

DEV u16 f2bf(float f){
  union { float f; u32 u; } x; x.f = f;
  return (u16)((x.u + 0x7FFFu + ((x.u >> 16) & 1u)) >> 16);
}
DEV float bf2f(u16 b){
  union { u32 u; float f; } x; x.u = ((u32)b) << 16; return x.f;
}
DEV f32x4 mfma16(short8 a, short8 b, f32x4 c){
  return __builtin_amdgcn_mfma_f32_16x16x32_bf16(a, b, c, 0, 0, 0);
}
DEV void g2l16(const void* g, void* l){
  __builtin_amdgcn_global_load_lds((const __attribute__((address_space(1))) u32*)g,
                                   (__attribute__((address_space(3))) u32*)l, 16, 0, 0);
}
DEV void wait_vm0(){ asm volatile("s_waitcnt vmcnt(0)" ::: "memory"); }

// ---------------------------------------------------------------------------
// Weight transpose + f32 -> bf16 (split-2 and single variants)
// ---------------------------------------------------------------------------
__global__ __launch_bounds__(256) void transpose_cvt2(const float* __restrict__ src,
    u16* __restrict__ dh, u16* __restrict__ dl, int R, int C)
{
  __shared__ float tile[32][33];
  const size_t zb = (size_t)blockIdx.z * R * C;
  src += zb; dh += zb; dl += zb;
  const int tx = threadIdx.x, ty = threadIdx.y;
  const int c0 = blockIdx.x * 32, r0 = blockIdx.y * 32;
  #pragma unroll
  for (int i = 0; i < 4; ++i)
    tile[ty + i*8][tx] = src[(size_t)(r0 + ty + i*8) * C + c0 + tx];
  __syncthreads();
  #pragma unroll
  for (int i = 0; i < 4; ++i){
    float v = tile[tx][ty + i*8];
    size_t o = (size_t)(c0 + ty + i*8) * R + r0 + tx;
    u16 hb = f2bf(v);
    dh[o] = hb;
    dl[o] = f2bf(v - bf2f(hb));
  }
}

__global__ __launch_bounds__(256) void transpose_cvt1(const float* __restrict__ src,
    u16* __restrict__ d, int R, int C)
{
  __shared__ float tile[32][33];
  const size_t zb = (size_t)blockIdx.z * R * C;
  src += zb; d += zb;
  const int tx = threadIdx.x, ty = threadIdx.y;
  const int c0 = blockIdx.x * 32, r0 = blockIdx.y * 32;
  #pragma unroll
  for (int i = 0; i < 4; ++i)
    tile[ty + i*8][tx] = src[(size_t)(r0 + ty + i*8) * C + c0 + tx];
  __syncthreads();
  #pragma unroll
  for (int i = 0; i < 4; ++i)
    d[(size_t)(c0 + ty + i*8) * R + r0 + tx] = f2bf(tile[tx][ty + i*8]);
}

// ---------------------------------------------------------------------------
// LN1: one wave per row, write y1 as split-2 bf16
// ---------------------------------------------------------------------------
__global__ __launch_bounds__(256) void ln1_kernel(const float* __restrict__ x,
    const float* __restrict__ g, const float* __restrict__ b,
    u16* __restrict__ yh, u16* __restrict__ yl)
{
  const int wid = threadIdx.x >> 6, lane = threadIdx.x & 63;
  const int row = blockIdx.x * 4 + wid;
  const float* xr = x + (size_t)row * 512 + lane * 8;
  f32x4 t0 = ((const f32x4*)xr)[0], t1 = ((const f32x4*)xr)[1];
  float v[8];
  #pragma unroll
  for (int j = 0; j < 8; ++j) v[j] = (j < 4) ? t0[j] : t1[j-4];
  float s = 0.f, q = 0.f;
  #pragma unroll
  for (int j = 0; j < 8; ++j){ s += v[j]; q += v[j]*v[j]; }
  #pragma unroll
  for (int o = 32; o; o >>= 1){ s += __shfl_xor(s, o); q += __shfl_xor(q, o); }
  const float mean = s * (1.f/512.f);
  const float var  = q * (1.f/512.f) - mean*mean;
  const float rstd = rsqrtf(var + 1e-5f);
  f32x4 g0 = ((const f32x4*)(g + lane*8))[0], g1 = ((const f32x4*)(g + lane*8))[1];
  f32x4 b0 = ((const f32x4*)(b + lane*8))[0], b1 = ((const f32x4*)(b + lane*8))[1];
  short8 vh, vl;
  #pragma unroll
  for (int j = 0; j < 8; ++j){
    float gg = (j < 4) ? g0[j] : g1[j-4];
    float bb = (j < 4) ? b0[j] : b1[j-4];
    float y = (v[j]-mean)*rstd*gg + bb;
    u16 hb = f2bf(y);
    vh[j] = (short)hb;
    vl[j] = (short)f2bf(y - bf2f(hb));
  }
  ((short8*)(yh + (size_t)row*512 + lane*8))[0] = vh;
  ((short8*)(yl + (size_t)row*512 + lane*8))[0] = vl;
}

// ---------------------------------------------------------------------------
// Split-2 GEMM: C = (Ah+Al) @ (Bh+Bl)^T, 3 MFMA passes. 128x128 tile, BK=32.
// 2-phase double-buffered K-loop. R6 swizzle: kcs = lg ^ ((row>>1)&3).
// ---------------------------------------------------------------------------
template<int MODE>
__global__ __launch_bounds__(256) void gemm_split2(
    const u16* __restrict__ Ah, const u16* __restrict__ Al,
    const u16* __restrict__ Bh, const u16* __restrict__ Bl,
    const float* __restrict__ bias, int K,
    u16* __restrict__ q_h, u16* __restrict__ q_l, u16* __restrict__ q_m,
    u16* __restrict__ k_h, u16* __restrict__ k_l, u16* __restrict__ k_m,
    u16* __restrict__ v_h, u16* __restrict__ v_l,
    const float* __restrict__ xres, float* __restrict__ hout)
{
  __shared__ u16 Ash[2][128*32], Asl[2][128*32], Bsh[2][128*32], Bsl[2][128*32];
  const int tid = threadIdx.x;
  const int wid = tid >> 6, lane = tid & 63;
  const int wr = wid >> 1, wc = wid & 1;
  const int lr = lane & 15, lg = lane >> 4;
  const int m0 = blockIdx.x * 128, n0 = blockIdx.y * 128;

  size_t aoff[2], boff[2];
  u32 ldso[2];
  #pragma unroll
  for (int r = 0; r < 2; ++r){
    int i = r*256 + tid;
    int row = i >> 2, cc = i & 3;
    int scc = cc ^ ((row >> 1) & 3);      // pre-swizzled source chunk (R6)
    aoff[r] = ((size_t)(m0+row)*K + scc*8) * 2;
    boff[r] = ((size_t)(n0+row)*K + scc*8) * 2;
    ldso[r] = (u32)(r*256 + wid*64) * 8;  // wave-uniform LDS base (shorts)
  }

  f32x4 acc[4][4];
  #pragma unroll
  for (int a = 0; a < 4; ++a)
    #pragma unroll
    for (int b = 0; b < 4; ++b) acc[a][b] = 0;

  const char* pAh = (const char*)Ah; const char* pAl = (const char*)Al;
  const char* pBh = (const char*)Bh; const char* pBl = (const char*)Bl;

  auto stage = [&](int sb, int ks){
    const size_t kb = (size_t)ks * 64;   // 32 elems * 2B
    #pragma unroll
    for (int r = 0; r < 2; ++r){
      g2l16(pAh + aoff[r] + kb, &Ash[sb][0] + ldso[r]);
      g2l16(pAl + aoff[r] + kb, &Asl[sb][0] + ldso[r]);
      g2l16(pBh + boff[r] + kb, &Bsh[sb][0] + ldso[r]);
      g2l16(pBl + boff[r] + kb, &Bsl[sb][0] + ldso[r]);
    }
  };

  const int nks = K >> 5;
  stage(0, 0);
  wait_vm0();
  __syncthreads();
  int buf = 0;
  for (int ks = 0; ks < nks; ++ks){
    if (ks + 1 < nks) stage(buf ^ 1, ks + 1);
    short8 ah[4], al[4], bh[4], bl[4];
    #pragma unroll
    for (int mt = 0; mt < 4; ++mt){
      int row = wr*64 + mt*16 + lr;
      int kcs = lg ^ ((row >> 1) & 3);
      int o = row*32 + kcs*8;
      ah[mt] = *(const short8*)(&Ash[buf][0] + o);
      al[mt] = *(const short8*)(&Asl[buf][0] + o);
    }
    #pragma unroll
    for (int nt = 0; nt < 4; ++nt){
      int row = wc*64 + nt*16 + lr;
      int kcs = lg ^ ((row >> 1) & 3);
      int o = row*32 + kcs*8;
      bh[nt] = *(const short8*)(&Bsh[buf][0] + o);
      bl[nt] = *(const short8*)(&Bsl[buf][0] + o);
    }
    __builtin_amdgcn_s_setprio(1);
    #pragma unroll
    for (int mt = 0; mt < 4; ++mt)
      #pragma unroll
      for (int nt = 0; nt < 4; ++nt){
        f32x4 c = acc[mt][nt];
        c = mfma16(ah[mt], bh[nt], c);
        c = mfma16(ah[mt], bl[nt], c);
        c = mfma16(al[mt], bh[nt], c);
        acc[mt][nt] = c;
      }
    __builtin_amdgcn_s_setprio(0);
    wait_vm0();
    __syncthreads();
    buf ^= 1;
  }

  #pragma unroll
  for (int mt = 0; mt < 4; ++mt){
    #pragma unroll
    for (int nt = 0; nt < 4; ++nt){
      const int col = n0 + wc*64 + nt*16 + lr;
      const float bv = bias[col];
      #pragma unroll
      for (int r2 = 0; r2 < 4; ++r2){
        const int row = m0 + wr*64 + mt*16 + 4*lg + r2;
        const float val = acc[mt][nt][r2] + bv;
        if constexpr (MODE == 0){
          const int which = col >> 9, rem = col & 511;
          const int hh = rem >> 6, hd = rem & 63;
          const int b_ = row >> 10, t_ = row & 1023;
          const size_t idx = ((size_t)(b_*8 + hh)*1024 + t_)*64 + hd;
          const u16 hb = f2bf(val);
          if (which == 2){
            v_h[idx] = hb;
            v_l[idx] = f2bf(val - bf2f(hb));
          } else {
            const float r1 = val - bf2f(hb);
            const u16 lb = f2bf(r1);
            const u16 mb = f2bf(r1 - bf2f(lb));
            if (which == 0){ q_h[idx]=hb; q_l[idx]=lb; q_m[idx]=mb; }
            else           { k_h[idx]=hb; k_l[idx]=lb; k_m[idx]=mb; }
          }
        } else {
          const size_t o = (size_t)row*512 + col;
          hout[o] = val + xres[o];
        }
      }
    }
  }
}

// ---------------------------------------------------------------------------
// Flash attention, causal. 64-row Q tiles, 4 waves (16 q-rows each), KV tiles 64.
// Q,K split-3 (6-pass QK^T), P,V split-2 (3-pass PV). Scores/softmax in f32.
// ---------------------------------------------------------------------------
__global__ __launch_bounds__(256) void attn_kernel(
    const u16* __restrict__ q_h, const u16* __restrict__ q_l, const u16* __restrict__ q_m,
    const u16* __restrict__ k_h, const u16* __restrict__ k_l, const u16* __restrict__ k_m,
    const u16* __restrict__ v_h, const u16* __restrict__ v_l,
    u16* __restrict__ aoh, u16* __restrict__ aol)
{
  __shared__ u16 Ksh[64*64], Ksl[64*64], Ksm[64*64];
  __shared__ u16 Vth[64*72], Vtl[64*72];
  __shared__ u16 Ph[4*16*72], Pl[4*16*72];
  const int tid = threadIdx.x, wid = tid >> 6, lane = tid & 63;
  const int lr = lane & 15, lg = lane >> 4;
  // LPT + XCD-affinity decode
  const int bfl = blockIdx.x;
  const int xcd = bfl & 7, jj_ = bfl >> 3;
  const int bh = xcd * 8 + (jj_ & 7);
  const int qt = 15 - (jj_ >> 3);
  const int q0 = qt * 64;
  const size_t base = (size_t)bh * 1024 * 64;

  short8 qfh[2], qfl[2], qfm[2];
  {
    const int qrow = q0 + wid*16 + lr;
    #pragma unroll
    for (int c = 0; c < 2; ++c){
      const size_t o = base + (size_t)qrow*64 + c*32 + lg*8;
      qfh[c] = *(const short8*)(q_h + o);
      qfl[c] = *(const short8*)(q_l + o);
      qfm[c] = *(const short8*)(q_m + o);
    }
  }
  f32x4 oacc[4];
  float m_r[4], l_r[4];
  #pragma unroll
  for (int nt = 0; nt < 4; ++nt) oacc[nt] = 0;
  #pragma unroll
  for (int r = 0; r < 4; ++r){ m_r[r] = -1e30f; l_r[r] = 0.f; }

  short8 kreg[3][2];
  short8 vreg[2][2];
  const int pp = tid & 31, d0 = (tid >> 5) * 8;

  auto load_tile = [&](int kt){
    #pragma unroll
    for (int r = 0; r < 2; ++r){
      const int i = r*256 + tid;
      const int row = i >> 3, cc = i & 7;
      const int scc = cc ^ (row & 7);       // pre-swizzled source chunk
      const size_t go = base + (size_t)(kt*64 + row)*64 + scc*8;
      kreg[0][r] = *(const short8*)(k_h + go);
      kreg[1][r] = *(const short8*)(k_l + go);
      kreg[2][r] = *(const short8*)(k_m + go);
    }
    const size_t g0 = base + (size_t)(kt*64 + 2*pp)*64 + d0;
    vreg[0][0] = *(const short8*)(v_h + g0);
    vreg[0][1] = *(const short8*)(v_h + g0 + 64);
    vreg[1][0] = *(const short8*)(v_l + g0);
    vreg[1][1] = *(const short8*)(v_l + g0 + 64);
  };

  load_tile(0);
  for (int kt = 0; kt <= qt; ++kt){
    if (kt) __syncthreads();               // prev compute done reading LDS
    #pragma unroll
    for (int r = 0; r < 2; ++r){
      const int o = (r*256 + tid) * 8;     // shorts, linear
      *(short8*)(Ksh + o) = kreg[0][r];
      *(short8*)(Ksl + o) = kreg[1][r];
      *(short8*)(Ksm + o) = kreg[2][r];
    }
    #pragma unroll
    for (int j = 0; j < 8; ++j){
      u32 ph_ = (u32)(u16)vreg[0][0][j] | ((u32)(u16)vreg[0][1][j] << 16);
      u32 pl_ = (u32)(u16)vreg[1][0][j] | ((u32)(u16)vreg[1][1][j] << 16);
      *(u32*)(Vth + (d0+j)*72 + 2*pp) = ph_;
      *(u32*)(Vtl + (d0+j)*72 + 2*pp) = pl_;
    }
    __syncthreads();
    if (kt < qt) load_tile(kt + 1);        // issue next-tile loads now
    __builtin_amdgcn_sched_barrier(0);     // pin issue point before compute

    // S = Q K^T (6-pass split-3)
    f32x4 s[4];
    #pragma unroll
    for (int nt = 0; nt < 4; ++nt) s[nt] = 0;
    __builtin_amdgcn_s_setprio(1);
    #pragma unroll
    for (int c = 0; c < 2; ++c){
      #pragma unroll
      for (int nt = 0; nt < 4; ++nt){
        const int row = nt*16 + lr;
        const int kcs = (c*4 + lg) ^ (row & 7);
        const int o = row*64 + kcs*8;
        short8 kh_ = *(const short8*)(Ksh + o);
        short8 kl_ = *(const short8*)(Ksl + o);
        short8 km_ = *(const short8*)(Ksm + o);
        f32x4 cacc = s[nt];
        cacc = mfma16(qfh[c], kh_, cacc);
        cacc = mfma16(qfh[c], kl_, cacc);
        cacc = mfma16(qfl[c], kh_, cacc);
        cacc = mfma16(qfh[c], km_, cacc);
        cacc = mfma16(qfm[c], kh_, cacc);
        cacc = mfma16(qfl[c], kl_, cacc);
        s[nt] = cacc;
      }
    }
    __builtin_amdgcn_s_setprio(0);
    // scale + causal mask
    float sc[4][4];
    const bool last = (kt == qt);
    #pragma unroll
    for (int nt = 0; nt < 4; ++nt)
      #pragma unroll
      for (int r = 0; r < 4; ++r){
        float v = s[nt][r] * 0.125f;
        if (last){
          int qa = q0 + wid*16 + 4*lg + r;
          int ka = kt*64 + nt*16 + lr;
          if (ka > qa) v = -1e30f;
        }
        sc[nt][r] = v;
      }
    // online softmax
    float pr[4][4];
    #pragma unroll
    for (int r = 0; r < 4; ++r){
      float mx = fmaxf(fmaxf(sc[0][r], sc[1][r]), fmaxf(sc[2][r], sc[3][r]));
      #pragma unroll
      for (int o2 = 8; o2; o2 >>= 1) mx = fmaxf(mx, __shfl_xor(mx, o2));
      const float nm = fmaxf(m_r[r], mx);
      const float al = __expf(m_r[r] - nm);
      float sum = 0.f;
      #pragma unroll
      for (int nt = 0; nt < 4; ++nt){
        float e_ = __expf(sc[nt][r] - nm);
        pr[nt][r] = e_;
        sum += e_;
      }
      #pragma unroll
      for (int o2 = 8; o2; o2 >>= 1) sum += __shfl_xor(sum, o2);
      l_r[r] = l_r[r]*al + sum;
      m_r[r] = nm;
      #pragma unroll
      for (int nt = 0; nt < 4; ++nt) oacc[nt][r] *= al;
    }
    // P -> per-wave LDS (split-2)
    #pragma unroll
    for (int nt = 0; nt < 4; ++nt)
      #pragma unroll
      for (int r = 0; r < 4; ++r){
        const float pv = pr[nt][r];
        const u16 hb = f2bf(pv);
        const u16 lb = f2bf(pv - bf2f(hb));
        const int o = wid*1152 + (4*lg + r)*72 + nt*16 + lr;
        Ph[o] = hb; Pl[o] = lb;
      }
    // O += P V (3-pass split-2)
    #pragma unroll
    for (int c = 0; c < 2; ++c){
      const int po = wid*1152 + lr*72 + c*32 + lg*8;
      short8 pah = *(const short8*)(Ph + po);
      short8 pal = *(const short8*)(Pl + po);
      __builtin_amdgcn_s_setprio(1);
      #pragma unroll
      for (int nt = 0; nt < 4; ++nt){
        const int vo = (nt*16 + lr)*72 + c*32 + lg*8;
        short8 vhf = *(const short8*)(Vth + vo);
        short8 vlf = *(const short8*)(Vtl + vo);
        f32x4 cacc = oacc[nt];
        cacc = mfma16(pah, vhf, cacc);
        cacc = mfma16(pah, vlf, cacc);
        cacc = mfma16(pal, vhf, cacc);
        oacc[nt] = cacc;
      }
      __builtin_amdgcn_s_setprio(0);
    }
  }

  const int b_ = bh >> 3, h_ = bh & 7;
  #pragma unroll
  for (int nt = 0; nt < 4; ++nt)
    #pragma unroll
    for (int r = 0; r < 4; ++r){
      const int qa = q0 + wid*16 + 4*lg + r;
      const float val = oacc[nt][r] / l_r[r];
      const size_t o = ((size_t)(b_*1024 + qa))*512 + h_*64 + nt*16 + lr;
      const u16 hb = f2bf(val);
      aoh[o] = hb;
      aol[o] = f2bf(val - bf2f(hb));
    }
}

// ---------------------------------------------------------------------------
// LN2 + gating: y2 bf16, logits in f32 (exact order-robust top-2). No atomics.
// ---------------------------------------------------------------------------
__global__ __launch_bounds__(256) void ln2_gate_kernel(const float* __restrict__ h,
    const float* __restrict__ g, const float* __restrict__ b,
    const float* __restrict__ Wg, u16* __restrict__ y2,
    int* __restrict__ ge, float* __restrict__ gw)
{
  const int wid = threadIdx.x >> 6, lane = threadIdx.x & 63;
  const int row = blockIdx.x * 4 + wid;
  const float* xr = h + (size_t)row * 512 + lane * 8;
  f32x4 t0 = ((const f32x4*)xr)[0], t1 = ((const f32x4*)xr)[1];
  float v[8];
  #pragma unroll
  for (int j = 0; j < 8; ++j) v[j] = (j < 4) ? t0[j] : t1[j-4];
  float s = 0.f, q = 0.f;
  #pragma unroll
  for (int j = 0; j < 8; ++j){ s += v[j]; q += v[j]*v[j]; }
  #pragma unroll
  for (int o = 32; o; o >>= 1){ s += __shfl_xor(s, o); q += __shfl_xor(q, o); }
  const float mean = s * (1.f/512.f);
  const float var  = q * (1.f/512.f) - mean*mean;
  const float rstd = rsqrtf(var + 1e-5f);
  f32x4 g0 = ((const f32x4*)(g + lane*8))[0], g1 = ((const f32x4*)(g + lane*8))[1];
  f32x4 b0 = ((const f32x4*)(b + lane*8))[0], b1 = ((const f32x4*)(b + lane*8))[1];
  float yv[8];
  short8 yb;
  #pragma unroll
  for (int j = 0; j < 8; ++j){
    float gg = (j < 4) ? g0[j] : g1[j-4];
    float bb = (j < 4) ? b0[j] : b1[j-4];
    yv[j] = (v[j]-mean)*rstd*gg + bb;
    yb[j] = (short)f2bf(yv[j]);
  }
  ((short8*)(y2 + (size_t)row*512 + lane*8))[0] = yb;

  float lgt[8];
  #pragma unroll
  for (int e = 0; e < 8; ++e) lgt[e] = 0.f;
  #pragma unroll
  for (int j = 0; j < 8; ++j){
    const float* wr_ = Wg + (size_t)(lane*8 + j) * 8;
    #pragma unroll
    for (int e = 0; e < 8; ++e) lgt[e] += yv[j] * wr_[e];
  }
  #pragma unroll
  for (int o = 32; o; o >>= 1){
    #pragma unroll
    for (int e = 0; e < 8; ++e) lgt[e] += __shfl_xor(lgt[e], o);
  }
  if (lane == 0){
    int e0 = 0; float l0 = lgt[0];
    #pragma unroll
    for (int e = 1; e < 8; ++e) if (lgt[e] > l0){ l0 = lgt[e]; e0 = e; }
    int e1 = -1; float l1 = -3e38f;
    #pragma unroll
    for (int e = 0; e < 8; ++e) if (e != e0 && lgt[e] > l1){ l1 = lgt[e]; e1 = e; }
    const float t = expf(l1 - l0);
    const float w0 = 1.f / (1.f + t);
    const float w1 = t * w0;
    ge[row*2]   = e0; ge[row*2+1] = e1;
    gw[row*2]   = w0; gw[row*2+1] = w1;
  }
}

// ---------------------------------------------------------------------------
// Routing bookkeeping. cnt layout: [0..7] counts, [8..15] offsets, [16] total,
// [17..24] cursors, [25..32] tile-prefix, [33] total tiles.
// ---------------------------------------------------------------------------
__global__ __launch_bounds__(256) void count_kernel(const int* __restrict__ ge,
                                                    int* __restrict__ cnt)
{
  const int i = blockIdx.x * 256 + threadIdx.x;   // 16384 entries
  const int lane = threadIdx.x & 63;
  const int e = ge[i];
  #pragma unroll
  for (int ex = 0; ex < 8; ++ex){
    u64 m = __ballot(e == ex);
    if (m && lane == (int)(__ffsll((long long)m) - 1))
      atomicAdd(&cnt[ex], __popcll(m));
  }
}

__global__ void offsets_kernel(int* cnt){
  if (threadIdx.x == 0){
    int o = 0, tp = 0;
    for (int e = 0; e < 8; ++e){
      cnt[8+e] = o; cnt[17+e] = o;
      cnt[25+e] = tp;
      o  += cnt[e];
      tp += (cnt[e] + 127) >> 7;
    }
    cnt[16] = o;
    cnt[33] = tp;
  }
}

__global__ __launch_bounds__(256) void scatter_kernel(const int* __restrict__ ge,
    const float* __restrict__ gw, int* __restrict__ cnt,
    int* __restrict__ rdst, float* __restrict__ rw)
{
  const int i = blockIdx.x * 256 + threadIdx.x;   // 16384 entries
  const int lane = threadIdx.x & 63;
  const int e = ge[i];
  const float w = gw[i];
  const u64 below = ((u64)1 << lane) - 1;
  int pos = -1;
  #pragma unroll
  for (int ex = 0; ex < 8; ++ex){
    u64 m = __ballot(e == ex);
    if (m){
      const int leader = (int)(__ffsll((long long)m) - 1);
      int base = 0;
      if (lane == leader) base = atomicAdd(&cnt[17 + ex], __popcll(m));
      base = __shfl(base, leader);
      if (e == ex) pos = base + __popcll(m & below);
    }
  }
  rdst[pos] = i;
  rw[pos]   = w;
}

// ---------------------------------------------------------------------------
// Grouped expert GEMM, plain bf16. 128x128 tile, BK=32, 2-phase dbuf K-loop.
// R6 conflict-free swizzle; R8 launch_bounds(256,4) (no spill).
// R9: round-robin band->XCD: band = bi*8 + xcd (was contiguous chunks that
// left XCDs 6,7 with zero real m-tiles). BAND_M=2 -> 68 bands over 8 XCDs
// (8-9 each); within a band n-major, m-fastest (A-band L2-hot across N sweep).
// MODE 2: hid[p] = gelu(y2[tok(p)] @ We1[e] + be1[e])
// MODE 3: contrib[dst(p)] = w(p) * (hid[p] @ We2[e] + be2[e])
// ---------------------------------------------------------------------------
template<int MODE, int TN, int BAND_M, int BPX>
__global__ __launch_bounds__(256, 4) void gemm_moe(
    const u16* __restrict__ A, const u16* __restrict__ Bt,
    const float* __restrict__ bias, int N, int K,
    const int* __restrict__ cntblk,
    const int* __restrict__ rdst, const float* __restrict__ rw,
    u16* __restrict__ hid, float* __restrict__ contrib)
{
  __shared__ u16 As[2][128*32], Bs[2][128*32];
  // --- round-robin band-supertile decode (bijective) ---
  const int fid = blockIdx.x;
  const int xcd = fid & 7;
  const int j   = fid >> 3;
  const int bpb = BAND_M * TN;           // blocks per band
  const int bi  = j / bpb;               // band round index on this XCD
  const int r_  = j % bpb;
  const int nt_ = r_ / BAND_M;           // n-tile (slow)
  const int mi  = r_ % BAND_M;           // m-tile within band (fast)
  const int mt  = (bi * 8 + xcd) * BAND_M + mi;    // round-robin bands
  if (mt >= cntblk[33]) return;
  int e = 7;
  #pragma unroll
  for (int k = 7; k >= 1; --k) if (mt < cntblk[25 + k]) e = k - 1;
  const int ce = cntblk[e];
  const int eo = cntblk[8 + e];
  const int m0 = (mt - cntblk[25 + e]) * 128;
  const int n0 = nt_ * 128;

  const int tid = threadIdx.x;
  const int wid = tid >> 6, lane = tid & 63;
  const int wr = wid >> 1, wc = wid & 1;
  const int lr = lane & 15, lg = lane >> 4;

  size_t aoff[2], boff[2];
  u32 ldso[2];
  #pragma unroll
  for (int r = 0; r < 2; ++r){
    int i = r*256 + tid;
    int row = i >> 2, cc = i & 3;
    int scc = cc ^ ((row >> 1) & 3);       // pre-swizzled source chunk (R6)
    int p = eo + m0 + row;
    const int pmax = eo + ce - 1;
    if (p > pmax) p = pmax;                // clamp tail rows to valid data
    const int arow = (MODE == 2) ? (rdst[p] >> 1) : p;
    aoff[r] = ((size_t)arow * K + scc*8) * 2;
    boff[r] = (((size_t)e * N + n0 + row) * K + scc*8) * 2;
    ldso[r] = (u32)(r*256 + wid*64) * 8;   // wave-uniform LDS base (shorts)
  }

  f32x4 acc[4][4];
  #pragma unroll
  for (int a = 0; a < 4; ++a)
    #pragma unroll
    for (int b = 0; b < 4; ++b) acc[a][b] = 0;

  const char* pA = (const char*)A;
  const char* pB = (const char*)Bt;

  auto stage = [&](int sb, int ks){
    const size_t kb = (size_t)ks * 64;     // 32 elems * 2B
    #pragma unroll
    for (int r = 0; r < 2; ++r){
      g2l16(pA + aoff[r] + kb, &As[sb][0] + ldso[r]);
      g2l16(pB + boff[r] + kb, &Bs[sb][0] + ldso[r]);
    }
  };

  const int nks = K >> 5;
  stage(0, 0);
  wait_vm0();
  __syncthreads();
  int buf = 0;
  for (int ks = 0; ks < nks; ++ks){
    if (ks + 1 < nks) stage(buf ^ 1, ks + 1);
    short8 av[4], bv[4];
    #pragma unroll
    for (int mt2 = 0; mt2 < 4; ++mt2){
      int row = wr*64 + mt2*16 + lr;
      int kcs = lg ^ ((row >> 1) & 3);
      av[mt2] = *(const short8*)(&As[buf][0] + row*32 + kcs*8);
    }
    #pragma unroll
    for (int nt2 = 0; nt2 < 4; ++nt2){
      int row = wc*64 + nt2*16 + lr;
      int kcs = lg ^ ((row >> 1) & 3);
      bv[nt2] = *(const short8*)(&Bs[buf][0] + row*32 + kcs*8);
    }
    __builtin_amdgcn_s_setprio(1);
    #pragma unroll
    for (int mt2 = 0; mt2 < 4; ++mt2)
      #pragma unroll
      for (int nt2 = 0; nt2 < 4; ++nt2)
        acc[mt2][nt2] = mfma16(av[mt2], bv[nt2], acc[mt2][nt2]);
    __builtin_amdgcn_s_setprio(0);
    wait_vm0();
    __syncthreads();
    buf ^= 1;
  }

  const float* bp = bias + (size_t)e * N;
  #pragma unroll
  for (int mt2 = 0; mt2 < 4; ++mt2){
    #pragma unroll
    for (int nt2 = 0; nt2 < 4; ++nt2){
      const int col = n0 + wc*64 + nt2*16 + lr;
      const float bv2 = bp[col];
      #pragma unroll
      for (int r2 = 0; r2 < 4; ++r2){
        const int lrow = wr*64 + mt2*16 + 4*lg + r2;
        if (m0 + lrow < ce){
          const int p = eo + m0 + lrow;
          const float val = acc[mt2][nt2][r2] + bv2;
          if constexpr (MODE == 2){
            // gelu: 0.5x(1+tanh z) == x * sigmoid(2z), exact identity
            const float gx = val;
            const float z2 = 1.5957691216057308f * (gx + 0.044715f*gx*gx*gx);
            const float gl = gx / (1.f + __expf(-z2));
            hid[(size_t)p * N + col] = f2bf(gl);
          } else {
            contrib[(size_t)rdst[p] * N + col] = val * rw[p];
          }
        }
      }
    }
  }
}

// ---------------------------------------------------------------------------
// out = h + contrib[2n] + contrib[2n+1]
// ---------------------------------------------------------------------------
__global__ __launch_bounds__(256) void final_kernel(const float* __restrict__ h,
    const float* __restrict__ contrib, float* __restrict__ out)
{
  const int i = blockIdx.x * 256 + threadIdx.x;   // 1,048,576 f32x4 groups
  const int row = i >> 7, rem = i & 127;
  const f32x4* c4 = (const f32x4*)contrib;
  f32x4 hv = ((const f32x4*)h)[i];
  f32x4 a = c4[(size_t)(row*2) * 128 + rem];
  f32x4 b = c4[(size_t)(row*2) * 128 + 128 + rem];
  ((f32x4*)out)[i] = hv + a + b;
}

// ---------------------------------------------------------------------------
extern "C" void kernel_launch(void* const* d_in, const int* in_sizes, int n_in,
                              void* d_out, int out_size, void* d_ws, size_t ws_size,
                              hipStream_t stream)
{
  (void)in_sizes; (void)n_in; (void)out_size; (void)ws_size;
  const float* x    = (const float*)d_in[0];
  const float* ln1g = (const float*)d_in[1];
  const float* ln1b = (const float*)d_in[2];
  const float* ln2g = (const float*)d_in[3];
  const float* ln2b = (const float*)d_in[4];
  const float* Wqkv = (const float*)d_in[5];
  const float* bqkv = (const float*)d_in[6];
  const float* Wo   = (const float*)d_in[7];
  const float* bo   = (const float*)d_in[8];
  const float* Wg   = (const float*)d_in[9];
  const float* We1  = (const float*)d_in[10];
  const float* be1  = (const float*)d_in[11];
  const float* We2  = (const float*)d_in[12];
  const float* be2  = (const float*)d_in[13];
  float* out = (float*)d_out;

  char* ws = (char*)d_ws;
  size_t off_ = 0;
  auto alloc = [&](size_t bytes)->char*{
    char* p = ws + off_;
    off_ = (off_ + bytes + 255) & ~(size_t)255;
    return p;
  };
  u16* wqkvTh = (u16*)alloc((size_t)1536*512*2);
  u16* wqkvTl = (u16*)alloc((size_t)1536*512*2);
  u16* woTh   = (u16*)alloc((size_t)512*512*2);
  u16* woTl   = (u16*)alloc((size_t)512*512*2);
  u16* we1T   = (u16*)alloc((size_t)8*2048*512*2);
  u16* we2T   = (u16*)alloc((size_t)8*512*2048*2);
  u16* y1h    = (u16*)alloc((size_t)8192*512*2);
  u16* y1l    = (u16*)alloc((size_t)8192*512*2);
  u16* qh_    = (u16*)alloc((size_t)8192*64*8*2);
  u16* ql_    = (u16*)alloc((size_t)8192*64*8*2);
  u16* qm_    = (u16*)alloc((size_t)8192*64*8*2);
  u16* kh_    = (u16*)alloc((size_t)8192*64*8*2);
  u16* kl_    = (u16*)alloc((size_t)8192*64*8*2);
  u16* km_    = (u16*)alloc((size_t)8192*64*8*2);
  u16* vh_    = (u16*)alloc((size_t)8192*64*8*2);
  u16* vl_    = (u16*)alloc((size_t)8192*64*8*2);
  u16* aoh    = (u16*)alloc((size_t)8192*512*2);
  u16* aol    = (u16*)alloc((size_t)8192*512*2);
  float* hbuf = (float*)alloc((size_t)8192*512*4);
  u16* y2     = (u16*)alloc((size_t)8192*512*2);
  int* ge     = (int*)alloc((size_t)8192*2*4);
  float* gw   = (float*)alloc((size_t)8192*2*4);
  int* cnt    = (int*)alloc(256);
  int* rdst   = (int*)alloc((size_t)16384*4);
  float* rw   = (float*)alloc((size_t)16384*4);
  u16* hid    = (u16*)alloc((size_t)16384*2048*2);
  float* contrib = (float*)alloc((size_t)16384*512*4);

  (void)hipMemsetAsync(cnt, 0, 256, stream);

  const dim3 tb(32, 8);
  transpose_cvt2<<<dim3(48, 16, 1), tb, 0, stream>>>(Wqkv, wqkvTh, wqkvTl, 512, 1536);
  transpose_cvt2<<<dim3(16, 16, 1), tb, 0, stream>>>(Wo,   woTh,   woTl,   512, 512);
  transpose_cvt1<<<dim3(64, 16, 8), tb, 0, stream>>>(We1, we1T, 512, 2048);
  transpose_cvt1<<<dim3(16, 64, 8), tb, 0, stream>>>(We2, we2T, 2048, 512);

  ln1_kernel<<<2048, 256, 0, stream>>>(x, ln1g, ln1b, y1h, y1l);

  gemm_split2<0><<<dim3(64, 12), 256, 0, stream>>>(
      y1h, y1l, wqkvTh, wqkvTl, bqkv, 512,
      qh_, ql_, qm_, kh_, kl_, km_, vh_, vl_, nullptr, nullptr);

  attn_kernel<<<dim3(1024), 256, 0, stream>>>(
      qh_, ql_, qm_, kh_, kl_, km_, vh_, vl_, aoh, aol);

  gemm_split2<1><<<dim3(64, 4), 256, 0, stream>>>(
      aoh, aol, woTh, woTl, bo, 512,
      nullptr, nullptr, nullptr, nullptr, nullptr, nullptr, nullptr, nullptr,
      x, hbuf);

  ln2_gate_kernel<<<2048, 256, 0, stream>>>(hbuf, ln2g, ln2b, Wg, y2, ge, gw);
  count_kernel<<<64, 256, 0, stream>>>(ge, cnt);
  offsets_kernel<<<1, 64, 0, stream>>>(cnt);
  scatter_kernel<<<64, 256, 0, stream>>>(ge, gw, cnt, rdst, rw);

  // moe2: 135 m-tiles, BAND_M=2 -> 68 bands round-robin over 8 XCDs, BPX=9
  // grid = 8 * 9 * 2 * 16 = 2304
  gemm_moe<2, 16, 2, 9><<<dim3(2304), 256, 0, stream>>>(
      y2, we1T, be1, 2048, 512, cnt, rdst, rw, hid, nullptr);
  // moe3: grid = 8 * 9 * 2 * 4 = 576
  gemm_moe<3, 4, 2, 9><<<dim3(576), 256, 0, stream>>>(
      hid, we2T, be2, 512, 2048, cnt, rdst, rw, nullptr, contrib);

  final_kernel<<<4096, 256, 0, stream>>>(hbuf, contrib, out);
}